// Round 14
// baseline (402.892 us; speedup 1.0000x reference)
//
#include <hip/hip_runtime.h>
#include <hip/hip_bf16.h>
#include <stdint.h>

#define T_TOK 4096
#define DIM   2048
#define HID   1024
#define NE    16
#define CAPE  512

typedef __bf16 bf16x8 __attribute__((ext_vector_type(8)));
typedef float  f32x4  __attribute__((ext_vector_type(4)));

__device__ __forceinline__ ushort f2bf(float f) {
    union { float f; uint32_t u; } v; v.f = f;
    uint32_t r = (v.u + 0x7FFFu + ((v.u >> 16) & 1u)) >> 16;
    return (ushort)r;
}
__device__ __forceinline__ float bf2f(ushort u) {
    union { uint32_t u; float f; } v; v.u = (uint32_t)u << 16; return v.f;
}
__device__ __forceinline__ void gload16(const void* g, void* lds) {
    __builtin_amdgcn_global_load_lds(
        (const __attribute__((address_space(1))) uint32_t*)g,
        (__attribute__((address_space(3))) uint32_t*)lds, 16, 0, 0);
}
#define VMCNT(n) asm volatile("s_waitcnt vmcnt(" #n ")" ::: "memory")

// ------ logits + x->bf16 convert: 16 tokens/block, LDS-staged gate weights ------
__global__ __launch_bounds__(256) void logits_kernel(
    const float* __restrict__ x, const float* __restrict__ gate_w,
    const float* __restrict__ coef_w, float* __restrict__ logits,
    ushort* __restrict__ xb)
{
    __shared__ float gws[18 * 512];   // [o][d-in-chunk], 36 KB
    int tid = threadIdx.x;
    int wv = tid >> 6, lane = tid & 63;
    int tbase = blockIdx.x * 16 + wv * 4;
    float acc[4][18];
#pragma unroll
    for (int tk = 0; tk < 4; ++tk)
#pragma unroll
        for (int o = 0; o < 18; ++o) acc[tk][o] = 0.f;

    for (int c = 0; c < 4; ++c) {
        int d0 = c * 512;
        __syncthreads();   // previous chunk's reads complete before restage
        const float4* g4 = (const float4*)(gate_w + (size_t)d0 * NE);
        for (int i = tid; i < 2048; i += 256) {
            float4 v = g4[i];
            int dd = i >> 2, o0 = (i & 3) * 4;
            gws[(o0 + 0) * 512 + dd] = v.x;
            gws[(o0 + 1) * 512 + dd] = v.y;
            gws[(o0 + 2) * 512 + dd] = v.z;
            gws[(o0 + 3) * 512 + dd] = v.w;
        }
        for (int i = tid; i < 1024; i += 256) {
            float v = coef_w[(size_t)d0 * 2 + i];
            gws[(16 + (i & 1)) * 512 + (i >> 1)] = v;
        }
        __syncthreads();
#pragma unroll
        for (int tk = 0; tk < 4; ++tk) {
            int t = tbase + tk;
            const float* xr = x + (size_t)t * DIM + d0;
            float xv[8];
#pragma unroll
            for (int j = 0; j < 8; ++j) xv[j] = xr[j * 64 + lane];
#pragma unroll
            for (int j = 0; j < 8; ++j)
                xb[(size_t)t * DIM + d0 + j * 64 + lane] = f2bf(xv[j]);
#pragma unroll
            for (int o = 0; o < 18; ++o) {
                const float* gr = &gws[o * 512 + lane];
                float a = acc[tk][o];
#pragma unroll
                for (int j = 0; j < 8; ++j) a += xv[j] * gr[j * 64];
                acc[tk][o] = a;
            }
        }
    }
#pragma unroll
    for (int tk = 0; tk < 4; ++tk) {
#pragma unroll
        for (int off = 32; off > 0; off >>= 1)
#pragma unroll
            for (int o = 0; o < 18; ++o)
                acc[tk][o] += __shfl_down(acc[tk][o], off, 64);
        if (lane == 0) {
#pragma unroll
            for (int o = 0; o < 18; ++o)
                logits[(size_t)(tbase + tk) * 18 + o] = acc[tk][o];
        }
    }
}

// ---------------- finish: one thread per token ----------------
__global__ __launch_bounds__(256) void finish_kernel(
    const float* __restrict__ logits, const float* __restrict__ coef_b,
    int* __restrict__ topidx, float* __restrict__ gatesw,
    float* __restrict__ coefo, float* __restrict__ probs_sum)
{
    __shared__ float wred[4][NE];
    int t = blockIdx.x * 256 + threadIdx.x;
    float lg[18];
#pragma unroll
    for (int o = 0; o < 18; ++o) lg[o] = logits[(size_t)t * 18 + o];
    float p[NE];
    float m = lg[0];
#pragma unroll
    for (int e = 1; e < NE; ++e) m = fmaxf(m, lg[e]);
    float ssum = 0.f;
#pragma unroll
    for (int e = 0; e < NE; ++e) { p[e] = expf(lg[e] - m); ssum += p[e]; }
    float inv = 1.f / ssum;
#pragma unroll
    for (int e = 0; e < NE; ++e) p[e] *= inv;
    int i1 = 0;
#pragma unroll
    for (int e = 1; e < NE; ++e) if (p[e] > p[i1]) i1 = e;
    int i2 = -1;
#pragma unroll
    for (int e = 0; e < NE; ++e) { if (e == i1) continue; if (i2 < 0 || p[e] > p[i2]) i2 = e; }
    float g0 = p[i1], g1 = p[i2], gs = g0 + g1;
    topidx[t * 2 + 0] = i1; topidx[t * 2 + 1] = i2;
    gatesw[t * 2 + 0] = g0 / gs; gatesw[t * 2 + 1] = g1 / gs;
    float c0 = lg[16] + coef_b[0], c1 = lg[17] + coef_b[1];
    float cm = fmaxf(c0, c1);
    float e0 = expf(c0 - cm), e1 = expf(c1 - cm);
    float cs = e0 + e1;
    coefo[t * 2 + 0] = e0 / cs; coefo[t * 2 + 1] = e1 / cs;

    float r[NE];
#pragma unroll
    for (int e = 0; e < NE; ++e) r[e] = p[e];
#pragma unroll
    for (int off = 32; off > 0; off >>= 1) {
#pragma unroll
        for (int e = 0; e < NE; ++e) r[e] += __shfl_down(r[e], off, 64);
    }
    int wv = threadIdx.x >> 6, ln = threadIdx.x & 63;
    if (ln == 0) {
#pragma unroll
        for (int e = 0; e < NE; ++e) wred[wv][e] = r[e];
    }
    __syncthreads();
    if (threadIdx.x < NE) {
        float s = wred[0][threadIdx.x] + wred[1][threadIdx.x]
                + wred[2][threadIdx.x] + wred[3][threadIdx.x];
        atomicAdd(&probs_sum[threadIdx.x], s);
    }
}

// -------- capacity scan: one block per expert (16 blocks), fills padding --------
__global__ __launch_bounds__(256) void scan_kernel(
    const int* __restrict__ topidx, const float* __restrict__ gatesw,
    const float* __restrict__ probs_sum,
    int* __restrict__ sidx, float* __restrict__ swt,
    int* __restrict__ assign_token, int* __restrict__ nvalid,
    float* __restrict__ out_tail)
{
    int e = blockIdx.x;
    __shared__ int wcnt[4];
    __shared__ int runs;
    __shared__ int cnt0s;
    int tid = threadIdx.x, wv = tid >> 6, ln = tid & 63;
    unsigned long long ltmask = (1ull << ln) - 1ull;
    if (tid == 0) runs = 0;
    __syncthreads();
    for (int kk = 0; kk < 2; ++kk) {
        for (int c = 0; c < T_TOK; c += 256) {
            int t = c + tid;
            bool m = (topidx[t * 2 + kk] == e);
            unsigned long long b = __ballot(m);
            int within = __popcll(b & ltmask);
            if (ln == 0) wcnt[wv] = __popcll(b);
            __syncthreads();
            int cross = 0;
            for (int w = 0; w < wv; ++w) cross += wcnt[w];
            int pos = runs + cross + within;
            if (m) {
                bool keep = pos < CAPE;
                sidx[t * 2 + kk] = keep ? (e * CAPE + pos) : -1;
                swt[t * 2 + kk] = keep ? gatesw[t * 2 + kk] : 0.f;
                if (keep) assign_token[e * CAPE + pos] = t;
            }
            __syncthreads();
            if (tid == 0) runs += wcnt[0] + wcnt[1] + wcnt[2] + wcnt[3];
            __syncthreads();
        }
        if (kk == 0 && tid == 0) cnt0s = runs;
        __syncthreads();
    }
    // fill padding slots (replaces host-side memset)
    for (int p = runs + tid; p < CAPE; p += 256)
        assign_token[e * CAPE + p] = 0;
    if (tid == 0) {
        int total = runs;
        nvalid[e] = min(CAPE, total);
        out_tail[1 + e] = (float)total;
        float term = (probs_sum[e] / (float)T_TOK) * ((float)cnt0s / (float)T_TOK) * (float)NE;
        atomicAdd(&out_tail[0], term);
    }
}

// ------- all weight transposes, 256x128 tiles, 512B read+write chunks -------
__global__ __launch_bounds__(256) void transpose_all(
    const float* __restrict__ w1, const float* __restrict__ w3,
    const float* __restrict__ w2, const float* __restrict__ sw1,
    const float* __restrict__ sw3, const float* __restrict__ sw2,
    ushort* __restrict__ w1T, ushort* __restrict__ w3T, ushort* __restrict__ w2T,
    ushort* __restrict__ sw1T, ushort* __restrict__ sw3T, ushort* __restrict__ sw2T)
{
    __shared__ __align__(16) ushort tile[128][264];
    int id = blockIdx.x;
    const float* in; ushort* outp; int R, C, tx, ty;
    if (id < 3072) {
        int seg = id >> 10;
        int rem = id & 1023;
        int e = rem >> 6;
        int r2 = rem & 63;
        if (seg < 2) {
            R = DIM; C = HID; tx = r2 & 7; ty = r2 >> 3;
            in   = (seg ? w3 : w1) + (size_t)e * DIM * HID;
            outp = (seg ? w3T : w1T) + (size_t)e * HID * DIM;
        } else {
            R = HID; C = DIM; tx = r2 & 3; ty = r2 >> 2;
            in   = w2 + (size_t)e * HID * DIM;
            outp = w2T + (size_t)e * DIM * HID;
        }
    } else {
        int id2 = id - 3072;
        int seg = id2 >> 6;
        int r2 = id2 & 63;
        if (seg < 2) {
            R = DIM; C = HID; tx = r2 & 7; ty = r2 >> 3;
            in = seg ? sw3 : sw1; outp = seg ? sw3T : sw1T;
        } else {
            R = HID; C = DIM; tx = r2 & 3; ty = r2 >> 2;
            in = sw2; outp = sw2T;
        }
    }
    int r0 = tx * 256, c0 = ty * 128;
    int tid = threadIdx.x;
    int t31 = tid & 31, t8 = tid >> 5;

#pragma unroll
    for (int it = 0; it < 8; ++it) {
        int r4 = (it * 8 + t8) * 4;
        int c4 = t31 * 4;
        const float* ip = in + (size_t)(r0 + r4) * C + c0 + c4;
        float va[4][4];
        *(float4*)va[0] = *(const float4*)(ip);
        *(float4*)va[1] = *(const float4*)(ip + C);
        *(float4*)va[2] = *(const float4*)(ip + 2 * (size_t)C);
        *(float4*)va[3] = *(const float4*)(ip + 3 * (size_t)C);
#pragma unroll
        for (int j = 0; j < 4; ++j) {
            uint2 u;
            u.x = (uint32_t)f2bf(va[0][j]) | ((uint32_t)f2bf(va[1][j]) << 16);
            u.y = (uint32_t)f2bf(va[2][j]) | ((uint32_t)f2bf(va[3][j]) << 16);
            *(uint2*)&tile[c4 + j][r4] = u;
        }
    }
    __syncthreads();

#pragma unroll
    for (int it = 0; it < 16; ++it) {
        int c = it * 8 + t8;
        int k = t31 * 8;
        uint4 o = *(const uint4*)&tile[c][k];
        *(uint4*)(outp + (size_t)(c0 + c) * R + r0 + k) = o;
    }
}

// ================= 8-phase MFMA GEMM cores (T2+T3+T4+T5) =================
__device__ __forceinline__ void stage_half_off(
    const ushort* __restrict__ G, int k0, char* region, int tid,
    size_t off0, size_t off1)
{
#pragma unroll
    for (int q = 0; q < 2; ++q) {
        int c = q * 512 + tid;
        int row = c >> 3;
        int cb = (c & 7) << 4;
        int scb = cb ^ ((row & 7) << 4);
        const ushort* src = G + (q ? off1 : off0) + k0 + (scb >> 1);
        gload16(src, region + ((c - (tid & 63)) << 4));
    }
}

__device__ __forceinline__ bf16x8 ldfrag(const char* lds, int region, int row, int cb) {
    return *(const bf16x8*)(lds + region + row * 128 + (cb ^ ((row & 7) << 4)));
}

// ---- single-B core: BM=256, B tile rows = NB*64 (NB=4 wide / NB=2 narrow) ----
template<int NB>
__device__ __forceinline__ void core_single(
    const ushort* __restrict__ A, const ushort* __restrict__ B,
    size_t a0, size_t a1, size_t a2, size_t a3,
    size_t b0, size_t b1, size_t b2, size_t b3,
    int K, char* lds, f32x4 (&acc)[8][NB], int tid)
{
    const int DB = 32768 + NB * 8192;
    int lane = tid & 63;
    int wid = tid >> 6;
    int wrow = wid >> 2, wcol = wid & 3;
    int l15 = lane & 15, hi = lane >> 4;

#pragma unroll
    for (int m = 0; m < 8; ++m)
#pragma unroll
        for (int n = 0; n < NB; ++n)
            acc[m][n] = (f32x4){0.f, 0.f, 0.f, 0.f};

    int nj = K >> 7;

    stage_half_off(A, 0, lds + 0,           tid, a0, a1);
    stage_half_off(A, 0, lds + 16384,       tid, a2, a3);
    stage_half_off(B, 0, lds + 32768,       tid, b0, b1);
    if (NB == 4) stage_half_off(B, 0, lds + 32768 + 16384, tid, b2, b3);
    stage_half_off(B, 64, lds + DB + 32768, tid, b0, b1);
    if (NB == 4) stage_half_off(B, 64, lds + DB + 32768 + 16384, tid, b2, b3);
    if (NB == 4) VMCNT(4); else VMCNT(2);
    __builtin_amdgcn_s_barrier();
    __builtin_amdgcn_sched_barrier(0);

    for (int j = 0; j < nj; ++j) {
        int k1 = (2 * j + 1) << 6, k2 = (2 * j + 2) << 6, k3 = (2 * j + 3) << 6;
        bool st = (j < nj - 1);
#pragma unroll
        for (int d = 0; d < 2; ++d) {
            char* LA = lds + d * DB;
            char* LB = LA + 32768;
            char* LAo = lds + (d ^ 1) * DB;
            bf16x8 bf[NB][2];
#pragma unroll
            for (int p = 0; p < 4; ++p) {
                if (p == 0) {
#pragma unroll
                    for (int n = 0; n < NB; ++n)
#pragma unroll
                        for (int ks = 0; ks < 2; ++ks)
                            bf[n][ks] = ldfrag(LB, 0, wcol * (16 * NB) + n * 16 + l15, ks * 64 + hi * 16);
                }
                bf16x8 af[2][2];
#pragma unroll
                for (int i = 0; i < 2; ++i)
#pragma unroll
                    for (int ks = 0; ks < 2; ++ks)
                        af[i][ks] = ldfrag(LA, 0, wrow * 128 + (2 * p + i) * 16 + l15, ks * 64 + hi * 16);
                if (d == 0) {
                    if (p == 0)      stage_half_off(A, k1, LAo,         tid, a0, a1);
                    else if (p == 1) stage_half_off(A, k1, LAo + 16384, tid, a2, a3);
                    else if (p == 2) { if (st) stage_half_off(B, k2, LB, tid, b0, b1); }
                    else             { if (st && NB == 4) stage_half_off(B, k2, LB + 16384, tid, b2, b3); }
                } else {
                    if (st) {
                        if (p == 0)      stage_half_off(A, k2, LAo,         tid, a0, a1);
                        else if (p == 1) stage_half_off(A, k2, LAo + 16384, tid, a2, a3);
                        else if (p == 2) stage_half_off(B, k3, LB, tid, b0, b1);
                        else             { if (NB == 4) stage_half_off(B, k3, LB + 16384, tid, b2, b3); }
                    }
                }
                __builtin_amdgcn_s_barrier();
                if (p == 3) {
                    if (d == 0) {
                        if (st) { if (NB == 4) VMCNT(4); else VMCNT(2); }
                        else    VMCNT(0);
                    } else if (st) {
                        if (NB == 4) VMCNT(4); else VMCNT(2);
                    }
                }
                asm volatile("s_waitcnt lgkmcnt(0)" ::: "memory");
                __builtin_amdgcn_sched_barrier(0);
                __builtin_amdgcn_s_setprio(1);
#pragma unroll
                for (int i = 0; i < 2; ++i)
#pragma unroll
                    for (int n = 0; n < NB; ++n)
#pragma unroll
                        for (int ks = 0; ks < 2; ++ks)
                            acc[2 * p + i][n] = __builtin_amdgcn_mfma_f32_16x16x32_bf16(
                                af[i][ks], bf[n][ks], acc[2 * p + i][n], 0, 0, 0);
                __builtin_amdgcn_s_setprio(0);
                __builtin_amdgcn_s_barrier();
                __builtin_amdgcn_sched_barrier(0);
            }
        }
    }
}

// ---- dual-B core: BM=256, per-matrix frags NM (2 wide / 1 narrow) ----
template<int NM>
__device__ __forceinline__ void core_dual(
    const ushort* __restrict__ A, const ushort* __restrict__ B1,
    const ushort* __restrict__ B3,
    size_t a0, size_t a1, size_t a2, size_t a3,
    size_t b0, size_t b1,
    int K, char* lds, f32x4 (&acc1)[8][NM], f32x4 (&acc3)[8][NM], int tid)
{
    const int DB = 32768 + NM * 16384;
    int lane = tid & 63;
    int wid = tid >> 6;
    int wrow = wid >> 2, wcol = wid & 3;
    int l15 = lane & 15, hi = lane >> 4;

#pragma unroll
    for (int m = 0; m < 8; ++m)
#pragma unroll
        for (int n = 0; n < NM; ++n) {
            acc1[m][n] = (f32x4){0.f, 0.f, 0.f, 0.f};
            acc3[m][n] = (f32x4){0.f, 0.f, 0.f, 0.f};
        }

    int nj = K >> 7;

    stage_half_off(A, 0, lds + 0,     tid, a0, a1);
    stage_half_off(A, 0, lds + 16384, tid, a2, a3);
    stage_half_off(B1, 0, lds + 32768, tid, b0, b1);
    if (NM == 2) stage_half_off(B3, 0, lds + 32768 + 16384, tid, b0, b1);
    stage_half_off(B1, 64, lds + DB + 32768, tid, b0, b1);
    if (NM == 2) stage_half_off(B3, 64, lds + DB + 32768 + 16384, tid, b0, b1);
    if (NM == 2) VMCNT(4); else VMCNT(2);
    __builtin_amdgcn_s_barrier();
    __builtin_amdgcn_sched_barrier(0);

    for (int j = 0; j < nj; ++j) {
        int k1 = (2 * j + 1) << 6, k2 = (2 * j + 2) << 6, k3 = (2 * j + 3) << 6;
        bool st = (j < nj - 1);
#pragma unroll
        for (int d = 0; d < 2; ++d) {
            char* LA = lds + d * DB;
            char* LB = LA + 32768;
            char* LAo = lds + (d ^ 1) * DB;
            bf16x8 bf1[NM][2], bf3[NM][2];
#pragma unroll
            for (int p = 0; p < 4; ++p) {
                if (p == 0) {
#pragma unroll
                    for (int n = 0; n < NM; ++n)
#pragma unroll
                        for (int ks = 0; ks < 2; ++ks) {
                            int brow = wcol * (16 * NM) + n * 16 + l15;
                            bf1[n][ks] = ldfrag(LB, 0, brow,           ks * 64 + hi * 16);
                            bf3[n][ks] = ldfrag(LB, 0, brow + NM * 64, ks * 64 + hi * 16);
                        }
                }
                bf16x8 af[2][2];
#pragma unroll
                for (int i = 0; i < 2; ++i)
#pragma unroll
                    for (int ks = 0; ks < 2; ++ks)
                        af[i][ks] = ldfrag(LA, 0, wrow * 128 + (2 * p + i) * 16 + l15, ks * 64 + hi * 16);
                if (d == 0) {
                    if (p == 0)      stage_half_off(A, k1, LAo,         tid, a0, a1);
                    else if (p == 1) stage_half_off(A, k1, LAo + 16384, tid, a2, a3);
                    else if (p == 2) { if (st) stage_half_off(B1, k2, LB, tid, b0, b1); }
                    else             { if (st && NM == 2) stage_half_off(B3, k2, LB + 16384, tid, b0, b1); }
                } else {
                    if (st) {
                        if (p == 0)      stage_half_off(A, k2, LAo,         tid, a0, a1);
                        else if (p == 1) stage_half_off(A, k2, LAo + 16384, tid, a2, a3);
                        else if (p == 2) stage_half_off(B1, k3, LB, tid, b0, b1);
                        else             { if (NM == 2) stage_half_off(B3, k3, LB + 16384, tid, b0, b1); }
                    }
                }
                __builtin_amdgcn_s_barrier();
                if (p == 3) {
                    if (d == 0) {
                        if (st) { if (NM == 2) VMCNT(4); else VMCNT(2); }
                        else    VMCNT(0);
                    } else if (st) {
                        if (NM == 2) VMCNT(4); else VMCNT(2);
                    }
                }
                asm volatile("s_waitcnt lgkmcnt(0)" ::: "memory");
                __builtin_amdgcn_sched_barrier(0);
                __builtin_amdgcn_s_setprio(1);
#pragma unroll
                for (int i = 0; i < 2; ++i)
#pragma unroll
                    for (int n = 0; n < NM; ++n)
#pragma unroll
                        for (int ks = 0; ks < 2; ++ks) {
                            acc1[2 * p + i][n] = __builtin_amdgcn_mfma_f32_16x16x32_bf16(
                                af[i][ks], bf1[n][ks], acc1[2 * p + i][n], 0, 0, 0);
                            acc3[2 * p + i][n] = __builtin_amdgcn_mfma_f32_16x16x32_bf16(
                                af[i][ks], bf3[n][ks], acc3[2 * p + i][n], 0, 0, 0);
                        }
                __builtin_amdgcn_s_setprio(0);
                __builtin_amdgcn_s_barrier();
                __builtin_amdgcn_sched_barrier(0);
            }
        }
    }
}

// up-projection, fused SiLU: 512 blocks = 256 expert (wide) + 256 shared (narrow)
__global__ __launch_bounds__(512, 2) void gemm8_up(
    const ushort* __restrict__ xb,
    const ushort* __restrict__ w1T, const ushort* __restrict__ w3T,
    const ushort* __restrict__ sw1T, const ushort* __restrict__ sw3T,
    const int* __restrict__ assign_token,
    ushort* __restrict__ HH, const int* __restrict__ nvalid)
{
    __shared__ __align__(16) char lds[131072];
    int b = blockIdx.x;
    int tid = threadIdx.x;
    int rr = tid >> 3;
    int lane = tid & 63, wid = tid >> 6;
    int wrow = wid >> 2, wcol = wid & 3;

    if (b < 256) {
        int id = (b & 7) * 32 + (b >> 3);
        int e = id >> 4, rem = id & 15;
        int mt = rem >> 3, nt = rem & 7;
        int bm = mt * 256, bn = nt * 128;
        if (bm >= nvalid[e]) return;
        const int* at = assign_token + e * CAPE + bm;
        size_t a0 = (size_t)at[rr] * DIM;
        size_t a1 = (size_t)at[64 + rr] * DIM;
        size_t a2 = (size_t)at[128 + rr] * DIM;
        size_t a3 = (size_t)at[192 + rr] * DIM;
        const ushort* B1 = w1T + (size_t)e * HID * DIM;
        const ushort* B3 = w3T + (size_t)e * HID * DIM;
        size_t b0 = (size_t)(bn + rr) * DIM;
        size_t b1 = (size_t)(bn + 64 + rr) * DIM;
        f32x4 acc1[8][2], acc3[8][2];
        core_dual<2>(xb, B1, B3, a0, a1, a2, a3, b0, b1, DIM, lds, acc1, acc3, tid);
        ushort* O = HH + (size_t)e * CAPE * HID;
        int rbase = bm + wrow * 128 + (lane >> 4) * 4;
        int cbase = bn + wcol * 32 + (lane & 15);
#pragma unroll
        for (int m = 0; m < 8; ++m)
#pragma unroll
            for (int n = 0; n < 2; ++n) {
                int col = cbase + n * 16;
#pragma unroll
                for (int r = 0; r < 4; ++r) {
                    float g = acc1[m][n][r];
                    float s = g / (1.f + __expf(-g));
                    O[(size_t)(rbase + m * 16 + r) * HID + col] = f2bf(s * acc3[m][n][r]);
                }
            }
    } else {
        int b2 = b - 256;
        int id = (b2 & 7) * 32 + (b2 >> 3);
        int mt = id >> 4, nt = id & 15;
        int bm = mt * 256, bn = nt * 64;
        size_t a0 = (size_t)(bm + rr) * DIM;
        size_t a1 = (size_t)(bm + 64 + rr) * DIM;
        size_t a2 = (size_t)(bm + 128 + rr) * DIM;
        size_t a3 = (size_t)(bm + 192 + rr) * DIM;
        size_t b0 = (size_t)(bn + rr) * DIM;
        size_t b1 = (size_t)(sw3T - sw1T) + (size_t)(bn + rr) * DIM;
        f32x4 acc1[8][1], acc3[8][1];
        core_dual<1>(xb, sw1T, sw1T, a0, a1, a2, a3, b0, b1, DIM, lds, acc1, acc3, tid);
        ushort* O = HH + (size_t)NE * CAPE * HID;
        int rbase = bm + wrow * 128 + (lane >> 4) * 4;
        int col = bn + wcol * 16 + (lane & 15);
#pragma unroll
        for (int m = 0; m < 8; ++m)
#pragma unroll
            for (int r = 0; r < 4; ++r) {
                float g = acc1[m][0][r];
                float s = g / (1.f + __expf(-g));
                O[(size_t)(rbase + m * 16 + r) * HID + col] = f2bf(s * acc3[m][0][r]);
            }
    }
}

// down-projection: 512 blocks = 256 expert wide (-> ye bf16) + 256 shared narrow (-> out f32)
__global__ __launch_bounds__(512, 2) void gemm8_down(
    const ushort* __restrict__ HH, const ushort* __restrict__ w2T,
    const ushort* __restrict__ sw2T, ushort* __restrict__ ye,
    float* __restrict__ outp, const float* __restrict__ coefo,
    const int* __restrict__ nvalid)
{
    __shared__ __align__(16) char lds[131072];
    int b = blockIdx.x;
    int tid = threadIdx.x;
    int rr = tid >> 3;
    int lane = tid & 63, wid = tid >> 6;
    int wrow = wid >> 2, wcol = wid & 3;

    if (b < 256) {
        int id = (b & 7) * 32 + (b >> 3);
        int e = id >> 4, rem = id & 15;
        int mt = rem >> 3, nt = rem & 7;
        int bm = mt * 256, bn = nt * 256;
        if (bm >= nvalid[e]) return;
        const ushort* A = HH + (size_t)e * CAPE * HID;
        const ushort* B = w2T + (size_t)e * DIM * HID;
        ushort* Ob = ye + (size_t)e * CAPE * DIM;
        size_t a0 = (size_t)(bm + rr) * HID;
        size_t a1 = (size_t)(bm + 64 + rr) * HID;
        size_t a2 = (size_t)(bm + 128 + rr) * HID;
        size_t a3 = (size_t)(bm + 192 + rr) * HID;
        size_t b0 = (size_t)(bn + rr) * HID;
        size_t b1 = (size_t)(bn + 64 + rr) * HID;
        size_t b2 = (size_t)(bn + 128 + rr) * HID;
        size_t b3 = (size_t)(bn + 192 + rr) * HID;
        f32x4 acc[8][4];
        core_single<4>(A, B, a0, a1, a2, a3, b0, b1, b2, b3, HID, lds, acc, tid);
        int rbase = bm + wrow * 128 + (lane >> 4) * 4;
        int cbase = bn + wcol * 64 + (lane & 15);
#pragma unroll
        for (int m = 0; m < 8; ++m)
#pragma unroll
            for (int n = 0; n < 4; ++n) {
                int col = cbase + n * 16;
#pragma unroll
                for (int r = 0; r < 4; ++r)
                    Ob[(size_t)(rbase + m * 16 + r) * DIM + col] = f2bf(acc[m][n][r]);
            }
    } else {
        int b2i = b - 256;
        int id = (b2i & 7) * 32 + (b2i >> 3);
        int mt = id >> 4, nt = id & 15;
        int bm = mt * 256, bn = nt * 128;
        const ushort* A = HH + (size_t)NE * CAPE * HID;
        const ushort* B = sw2T;
        size_t a0 = (size_t)(bm + rr) * HID;
        size_t a1 = (size_t)(bm + 64 + rr) * HID;
        size_t a2 = (size_t)(bm + 128 + rr) * HID;
        size_t a3 = (size_t)(bm + 192 + rr) * HID;
        size_t b0 = (size_t)(bn + rr) * HID;
        size_t b1 = (size_t)(bn + 64 + rr) * HID;
        f32x4 acc[8][2];
        core_single<2>(A, B, a0, a1, a2, a3, b0, b1, 0, 0, HID, lds, acc, tid);
        int rbase = bm + wrow * 128 + (lane >> 4) * 4;
        int cbase = bn + wcol * 32 + (lane & 15);
#pragma unroll
        for (int m = 0; m < 8; ++m)
#pragma unroll
            for (int n = 0; n < 2; ++n) {
                int col = cbase + n * 16;
#pragma unroll
                for (int r = 0; r < 4; ++r) {
                    int row = rbase + m * 16 + r;
                    outp[(size_t)row * DIM + col] = acc[m][n][r] * coefo[2 * row + 1];
                }
            }
    }
}

// ---------------- final combine: out += coef0*(w0*ye[s0] + w1*ye[s1]) ----------------
__global__ __launch_bounds__(256) void combine_kernel(
    const ushort* __restrict__ ye, const int* __restrict__ sidx,
    const float* __restrict__ swt, const float* __restrict__ coefo,
    float* __restrict__ out)
{
    int idx = blockIdx.x * 256 + threadIdx.x;
    int t = idx >> 9;
    int d = (idx & 511) << 2;
    int s0 = sidx[t * 2], s1 = sidx[t * 2 + 1];
    float c0 = coefo[t * 2];
    float w0 = swt[t * 2] * c0, w1 = swt[t * 2 + 1] * c0;
    float4 v = *(float4*)(out + (size_t)t * DIM + d);
    if (s0 >= 0) {
        uint2 y = *(const uint2*)(ye + (size_t)s0 * DIM + d);
        const ushort* yp = (const ushort*)&y;
        v.x += w0 * bf2f(yp[0]); v.y += w0 * bf2f(yp[1]);
        v.z += w0 * bf2f(yp[2]); v.w += w0 * bf2f(yp[3]);
    }
    if (s1 >= 0) {
        uint2 y = *(const uint2*)(ye + (size_t)s1 * DIM + d);
        const ushort* yp = (const ushort*)&y;
        v.x += w1 * bf2f(yp[0]); v.y += w1 * bf2f(yp[1]);
        v.z += w1 * bf2f(yp[2]); v.w += w1 * bf2f(yp[3]);
    }
    *(float4*)(out + (size_t)t * DIM + d) = v;
}

extern "C" void kernel_launch(void* const* d_in, const int* in_sizes, int n_in,
                              void* d_out, int out_size, void* d_ws, size_t ws_size,
                              hipStream_t stream)
{
    const float* x      = (const float*)d_in[0];
    const float* gate_w = (const float*)d_in[1];
    const float* w1     = (const float*)d_in[2];
    const float* w3     = (const float*)d_in[3];
    const float* w2     = (const float*)d_in[4];
    const float* sw1    = (const float*)d_in[5];
    const float* sw3    = (const float*)d_in[6];
    const float* sw2    = (const float*)d_in[7];
    const float* coef_w = (const float*)d_in[8];
    const float* coef_b = (const float*)d_in[9];
    float* out = (float*)d_out;

    char* ws = (char*)d_ws;
    size_t off = 0;
    auto alloc = [&](size_t bytes) -> void* {
        void* p = ws + off;
        off += (bytes + 255) & ~(size_t)255;
        return p;
    };
    float*  probs_sum    = (float*)alloc(NE * 4);
    int*    nvalid       = (int*)alloc(NE * 4);
    int*    topidx       = (int*)alloc((size_t)T_TOK * 2 * 4);
    float*  gatesw       = (float*)alloc((size_t)T_TOK * 2 * 4);
    float*  coefo        = (float*)alloc((size_t)T_TOK * 2 * 4);
    int*    sidx         = (int*)alloc((size_t)T_TOK * 2 * 4);
    float*  swt          = (float*)alloc((size_t)T_TOK * 2 * 4);
    int*    assign_token = (int*)alloc((size_t)NE * CAPE * 4);
    float*  logits       = (float*)alloc((size_t)T_TOK * 18 * 4);
    ushort* w1T  = (ushort*)alloc((size_t)NE * HID * DIM * 2);
    ushort* w3T  = (ushort*)alloc((size_t)NE * HID * DIM * 2);
    ushort* w2T  = (ushort*)alloc((size_t)NE * DIM * HID * 2);
    ushort* sw1T = (ushort*)alloc((size_t)HID * DIM * 2);
    ushort* sw3T = (ushort*)alloc((size_t)HID * DIM * 2);
    ushort* sw2T = (ushort*)alloc((size_t)DIM * HID * 2);
    ushort* xb   = (ushort*)alloc((size_t)T_TOK * DIM * 2);
    size_t HROWS = (size_t)NE * CAPE + T_TOK;
    ushort* HH   = (ushort*)alloc(HROWS * HID * 2);
    ushort* ye   = (ushort*)alloc((size_t)NE * CAPE * DIM * 2);

    hipMemsetAsync(probs_sum, 0, NE * 4, stream);
    hipMemsetAsync(out + (size_t)T_TOK * DIM, 0, 4, stream);  // l_aux accumulator

    logits_kernel<<<T_TOK / 16, 256, 0, stream>>>(x, gate_w, coef_w, logits, xb);
    finish_kernel<<<T_TOK / 256, 256, 0, stream>>>(logits, coef_b,
                                                   topidx, gatesw, coefo, probs_sum);
    scan_kernel<<<NE, 256, 0, stream>>>(topidx, gatesw, probs_sum,
                                        sidx, swt, assign_token, nvalid,
                                        out + (size_t)T_TOK * DIM);

    transpose_all<<<3264, 256, 0, stream>>>(w1, w3, w2, sw1, sw3, sw2,
                                            w1T, w3T, w2T, sw1T, sw3T, sw2T);

    gemm8_up<<<512, 512, 0, stream>>>(xb, w1T, w3T, sw1T, sw3T, assign_token, HH, nvalid);
    gemm8_down<<<512, 512, 0, stream>>>(HH, w2T, sw2T, ye, out, coefo, nvalid);

    combine_kernel<<<(T_TOK * (DIM / 4)) / 256, 256, 0, stream>>>(ye, sidx, swt, coefo, out);
}

// Round 15
// 400.512 us; speedup vs baseline: 1.0059x; 1.0059x over previous
//
#include <hip/hip_runtime.h>
#include <hip/hip_bf16.h>
#include <stdint.h>

#define T_TOK 4096
#define DIM   2048
#define HID   1024
#define NE    16
#define CAPE  512

typedef __bf16 bf16x8 __attribute__((ext_vector_type(8)));
typedef float  f32x4  __attribute__((ext_vector_type(4)));

__device__ __forceinline__ ushort f2bf(float f) {
    union { float f; uint32_t u; } v; v.f = f;
    uint32_t r = (v.u + 0x7FFFu + ((v.u >> 16) & 1u)) >> 16;
    return (ushort)r;
}
__device__ __forceinline__ float bf2f(ushort u) {
    union { uint32_t u; float f; } v; v.u = (uint32_t)u << 16; return v.f;
}
__device__ __forceinline__ void gload16(const void* g, void* lds) {
    __builtin_amdgcn_global_load_lds(
        (const __attribute__((address_space(1))) uint32_t*)g,
        (__attribute__((address_space(3))) uint32_t*)lds, 16, 0, 0);
}
#define VMCNT(n) asm volatile("s_waitcnt vmcnt(" #n ")" ::: "memory")

// ------ logits + x->bf16 convert + FUSED finish: 16 tokens/block ------
__global__ __launch_bounds__(256) void logits_kernel(
    const float* __restrict__ x, const float* __restrict__ gate_w,
    const float* __restrict__ coef_w, const float* __restrict__ coef_b,
    ushort* __restrict__ xb,
    int* __restrict__ topidx, float* __restrict__ gatesw,
    float* __restrict__ coefo, float* __restrict__ probs_part,
    float* __restrict__ laux)
{
    __shared__ float gws[18 * 512];   // [o][d-in-chunk], 36 KB
    __shared__ float wred[4][NE];
    int tid = threadIdx.x;
    int wv = tid >> 6, lane = tid & 63;
    int tbase = blockIdx.x * 16 + wv * 4;
    float acc[4][18];
#pragma unroll
    for (int tk = 0; tk < 4; ++tk)
#pragma unroll
        for (int o = 0; o < 18; ++o) acc[tk][o] = 0.f;

    for (int c = 0; c < 4; ++c) {
        int d0 = c * 512;
        __syncthreads();
        const float4* g4 = (const float4*)(gate_w + (size_t)d0 * NE);
        for (int i = tid; i < 2048; i += 256) {
            float4 v = g4[i];
            int dd = i >> 2, o0 = (i & 3) * 4;
            gws[(o0 + 0) * 512 + dd] = v.x;
            gws[(o0 + 1) * 512 + dd] = v.y;
            gws[(o0 + 2) * 512 + dd] = v.z;
            gws[(o0 + 3) * 512 + dd] = v.w;
        }
        for (int i = tid; i < 1024; i += 256) {
            float v = coef_w[(size_t)d0 * 2 + i];
            gws[(16 + (i & 1)) * 512 + (i >> 1)] = v;
        }
        __syncthreads();
#pragma unroll
        for (int tk = 0; tk < 4; ++tk) {
            int t = tbase + tk;
            const float* xr = x + (size_t)t * DIM + d0;
            float xv[8];
#pragma unroll
            for (int j = 0; j < 8; ++j) xv[j] = xr[j * 64 + lane];
#pragma unroll
            for (int j = 0; j < 8; ++j)
                xb[(size_t)t * DIM + d0 + j * 64 + lane] = f2bf(xv[j]);
#pragma unroll
            for (int o = 0; o < 18; ++o) {
                const float* gr = &gws[o * 512 + lane];
                float a = acc[tk][o];
#pragma unroll
                for (int j = 0; j < 8; ++j) a += xv[j] * gr[j * 64];
                acc[tk][o] = a;
            }
        }
    }
#pragma unroll
    for (int tk = 0; tk < 4; ++tk)
#pragma unroll
        for (int off = 32; off > 0; off >>= 1)
#pragma unroll
            for (int o = 0; o < 18; ++o)
                acc[tk][o] += __shfl_down(acc[tk][o], off, 64);

    // fused finish: lane 0 holds full logits for its 4 tokens
    if (lane == 0) {
        float ps[NE];
#pragma unroll
        for (int e = 0; e < NE; ++e) ps[e] = 0.f;
#pragma unroll
        for (int tk = 0; tk < 4; ++tk) {
            int t = tbase + tk;
            float lg[18];
#pragma unroll
            for (int o = 0; o < 18; ++o) lg[o] = acc[tk][o];
            float m = lg[0];
#pragma unroll
            for (int e = 1; e < NE; ++e) m = fmaxf(m, lg[e]);
            float p[NE];
            float ssum = 0.f;
#pragma unroll
            for (int e = 0; e < NE; ++e) { p[e] = expf(lg[e] - m); ssum += p[e]; }
            float inv = 1.f / ssum;
#pragma unroll
            for (int e = 0; e < NE; ++e) p[e] *= inv;
            int i1 = 0;
#pragma unroll
            for (int e = 1; e < NE; ++e) if (p[e] > p[i1]) i1 = e;
            int i2 = -1;
#pragma unroll
            for (int e = 0; e < NE; ++e) { if (e == i1) continue; if (i2 < 0 || p[e] > p[i2]) i2 = e; }
            float g0 = p[i1], g1 = p[i2], gs = g0 + g1;
            topidx[t * 2 + 0] = i1; topidx[t * 2 + 1] = i2;
            gatesw[t * 2 + 0] = g0 / gs; gatesw[t * 2 + 1] = g1 / gs;
            float c0 = lg[16] + coef_b[0], c1 = lg[17] + coef_b[1];
            float cm = fmaxf(c0, c1);
            float e0 = expf(c0 - cm), e1 = expf(c1 - cm);
            float cs = e0 + e1;
            coefo[t * 2 + 0] = e0 / cs; coefo[t * 2 + 1] = e1 / cs;
#pragma unroll
            for (int e = 0; e < NE; ++e) ps[e] += p[e];
        }
#pragma unroll
        for (int e = 0; e < NE; ++e) wred[wv][e] = ps[e];
    }
    __syncthreads();
    if (tid < NE)
        probs_part[blockIdx.x * NE + tid] =
            wred[0][tid] + wred[1][tid] + wred[2][tid] + wred[3][tid];
    if (blockIdx.x == 0 && tid == 0) laux[0] = 0.f;
}

// ==== merged scan (blocks 0..15) + weight transposes (blocks 16..3279) ====
__global__ __launch_bounds__(256) void scan_transpose(
    const int* __restrict__ topidx, const float* __restrict__ gatesw,
    const float* __restrict__ probs_part,
    int* __restrict__ sidx, float* __restrict__ swt,
    int* __restrict__ assign_token, int* __restrict__ nvalid,
    float* __restrict__ out_tail,
    const float* __restrict__ w1, const float* __restrict__ w3,
    const float* __restrict__ w2, const float* __restrict__ sw1,
    const float* __restrict__ sw3, const float* __restrict__ sw2,
    ushort* __restrict__ w1T, ushort* __restrict__ w3T, ushort* __restrict__ w2T,
    ushort* __restrict__ sw1T, ushort* __restrict__ sw3T, ushort* __restrict__ sw2T)
{
    __shared__ __align__(16) ushort tile[128][264];
    int tid = threadIdx.x;

    if (blockIdx.x < NE) {
        // ---------------- capacity scan: one block per expert ----------------
        __shared__ int wcnt[4];
        __shared__ float fred[4];
        __shared__ int runs;
        __shared__ int cnt0s;
        int e = blockIdx.x;
        int wv = tid >> 6, ln = tid & 63;
        unsigned long long ltmask = (1ull << ln) - 1ull;
        if (tid == 0) runs = 0;
        __syncthreads();
        for (int kk = 0; kk < 2; ++kk) {
            for (int c = 0; c < T_TOK; c += 256) {
                int t = c + tid;
                bool m = (topidx[t * 2 + kk] == e);
                unsigned long long b = __ballot(m);
                int within = __popcll(b & ltmask);
                if (ln == 0) wcnt[wv] = __popcll(b);
                __syncthreads();
                int cross = 0;
                for (int w = 0; w < wv; ++w) cross += wcnt[w];
                int pos = runs + cross + within;
                if (m) {
                    bool keep = pos < CAPE;
                    sidx[t * 2 + kk] = keep ? (e * CAPE + pos) : -1;
                    swt[t * 2 + kk] = keep ? gatesw[t * 2 + kk] : 0.f;
                    if (keep) assign_token[e * CAPE + pos] = t;
                }
                __syncthreads();
                if (tid == 0) runs += wcnt[0] + wcnt[1] + wcnt[2] + wcnt[3];
                __syncthreads();
            }
            if (kk == 0 && tid == 0) cnt0s = runs;
            __syncthreads();
        }
        for (int p = runs + tid; p < CAPE; p += 256)
            assign_token[e * CAPE + p] = 0;
        // reduce probs_part over 256 blocks for this expert
        float val = probs_part[tid * NE + e];
#pragma unroll
        for (int off = 32; off > 0; off >>= 1) val += __shfl_down(val, off, 64);
        if (ln == 0) fred[wv] = val;
        __syncthreads();
        if (tid == 0) {
            float psum = fred[0] + fred[1] + fred[2] + fred[3];
            int total = runs;
            nvalid[e] = min(CAPE, total);
            out_tail[1 + e] = (float)total;
            float term = (psum / (float)T_TOK) * ((float)cnt0s / (float)T_TOK) * (float)NE;
            atomicAdd(&out_tail[0], term);
        }
        return;
    }

    // ---------------- transpose tile: f32 [R][C] -> bf16 [C][R] ----------------
    int id = blockIdx.x - NE;
    const float* in; ushort* outp; int R, C, tx, ty;
    if (id < 3072) {
        int seg = id >> 10;
        int rem = id & 1023;
        int e = rem >> 6;
        int r2 = rem & 63;
        if (seg < 2) {
            R = DIM; C = HID; tx = r2 & 7; ty = r2 >> 3;
            in   = (seg ? w3 : w1) + (size_t)e * DIM * HID;
            outp = (seg ? w3T : w1T) + (size_t)e * HID * DIM;
        } else {
            R = HID; C = DIM; tx = r2 & 3; ty = r2 >> 2;
            in   = w2 + (size_t)e * HID * DIM;
            outp = w2T + (size_t)e * DIM * HID;
        }
    } else {
        int id2 = id - 3072;
        int seg = id2 >> 6;
        int r2 = id2 & 63;
        if (seg < 2) {
            R = DIM; C = HID; tx = r2 & 7; ty = r2 >> 3;
            in = seg ? sw3 : sw1; outp = seg ? sw3T : sw1T;
        } else {
            R = HID; C = DIM; tx = r2 & 3; ty = r2 >> 2;
            in = sw2; outp = sw2T;
        }
    }
    int r0 = tx * 256, c0 = ty * 128;
    int t31 = tid & 31, t8 = tid >> 5;

#pragma unroll
    for (int it = 0; it < 8; ++it) {
        int r4 = (it * 8 + t8) * 4;
        int c4 = t31 * 4;
        const float* ip = in + (size_t)(r0 + r4) * C + c0 + c4;
        float va[4][4];
        *(float4*)va[0] = *(const float4*)(ip);
        *(float4*)va[1] = *(const float4*)(ip + C);
        *(float4*)va[2] = *(const float4*)(ip + 2 * (size_t)C);
        *(float4*)va[3] = *(const float4*)(ip + 3 * (size_t)C);
#pragma unroll
        for (int j = 0; j < 4; ++j) {
            uint2 u;
            u.x = (uint32_t)f2bf(va[0][j]) | ((uint32_t)f2bf(va[1][j]) << 16);
            u.y = (uint32_t)f2bf(va[2][j]) | ((uint32_t)f2bf(va[3][j]) << 16);
            *(uint2*)&tile[c4 + j][r4] = u;
        }
    }
    __syncthreads();

#pragma unroll
    for (int it = 0; it < 16; ++it) {
        int c = it * 8 + t8;
        int k = t31 * 8;
        uint4 o = *(const uint4*)&tile[c][k];
        *(uint4*)(outp + (size_t)(c0 + c) * R + r0 + k) = o;
    }
}

// ================= 8-phase MFMA GEMM cores (T2+T3+T4+T5) =================
__device__ __forceinline__ void stage_half_off(
    const ushort* __restrict__ G, int k0, char* region, int tid,
    size_t off0, size_t off1)
{
#pragma unroll
    for (int q = 0; q < 2; ++q) {
        int c = q * 512 + tid;
        int row = c >> 3;
        int cb = (c & 7) << 4;
        int scb = cb ^ ((row & 7) << 4);
        const ushort* src = G + (q ? off1 : off0) + k0 + (scb >> 1);
        gload16(src, region + ((c - (tid & 63)) << 4));
    }
}

__device__ __forceinline__ bf16x8 ldfrag(const char* lds, int region, int row, int cb) {
    return *(const bf16x8*)(lds + region + row * 128 + (cb ^ ((row & 7) << 4)));
}

// ---- single-B core: BM=256, B tile rows = NB*64 (NB=4 wide / NB=2 narrow) ----
template<int NB>
__device__ __forceinline__ void core_single(
    const ushort* __restrict__ A, const ushort* __restrict__ B,
    size_t a0, size_t a1, size_t a2, size_t a3,
    size_t b0, size_t b1, size_t b2, size_t b3,
    int K, char* lds, f32x4 (&acc)[8][NB], int tid)
{
    const int DB = 32768 + NB * 8192;
    int lane = tid & 63;
    int wid = tid >> 6;
    int wrow = wid >> 2, wcol = wid & 3;
    int l15 = lane & 15, hi = lane >> 4;

#pragma unroll
    for (int m = 0; m < 8; ++m)
#pragma unroll
        for (int n = 0; n < NB; ++n)
            acc[m][n] = (f32x4){0.f, 0.f, 0.f, 0.f};

    int nj = K >> 7;

    stage_half_off(A, 0, lds + 0,           tid, a0, a1);
    stage_half_off(A, 0, lds + 16384,       tid, a2, a3);
    stage_half_off(B, 0, lds + 32768,       tid, b0, b1);
    if (NB == 4) stage_half_off(B, 0, lds + 32768 + 16384, tid, b2, b3);
    stage_half_off(B, 64, lds + DB + 32768, tid, b0, b1);
    if (NB == 4) stage_half_off(B, 64, lds + DB + 32768 + 16384, tid, b2, b3);
    if (NB == 4) VMCNT(4); else VMCNT(2);
    __builtin_amdgcn_s_barrier();
    __builtin_amdgcn_sched_barrier(0);

    for (int j = 0; j < nj; ++j) {
        int k1 = (2 * j + 1) << 6, k2 = (2 * j + 2) << 6, k3 = (2 * j + 3) << 6;
        bool st = (j < nj - 1);
#pragma unroll
        for (int d = 0; d < 2; ++d) {
            char* LA = lds + d * DB;
            char* LB = LA + 32768;
            char* LAo = lds + (d ^ 1) * DB;
            bf16x8 bf[NB][2];
#pragma unroll
            for (int p = 0; p < 4; ++p) {
                if (p == 0) {
#pragma unroll
                    for (int n = 0; n < NB; ++n)
#pragma unroll
                        for (int ks = 0; ks < 2; ++ks)
                            bf[n][ks] = ldfrag(LB, 0, wcol * (16 * NB) + n * 16 + l15, ks * 64 + hi * 16);
                }
                bf16x8 af[2][2];
#pragma unroll
                for (int i = 0; i < 2; ++i)
#pragma unroll
                    for (int ks = 0; ks < 2; ++ks)
                        af[i][ks] = ldfrag(LA, 0, wrow * 128 + (2 * p + i) * 16 + l15, ks * 64 + hi * 16);
                if (d == 0) {
                    if (p == 0)      stage_half_off(A, k1, LAo,         tid, a0, a1);
                    else if (p == 1) stage_half_off(A, k1, LAo + 16384, tid, a2, a3);
                    else if (p == 2) { if (st) stage_half_off(B, k2, LB, tid, b0, b1); }
                    else             { if (st && NB == 4) stage_half_off(B, k2, LB + 16384, tid, b2, b3); }
                } else {
                    if (st) {
                        if (p == 0)      stage_half_off(A, k2, LAo,         tid, a0, a1);
                        else if (p == 1) stage_half_off(A, k2, LAo + 16384, tid, a2, a3);
                        else if (p == 2) stage_half_off(B, k3, LB, tid, b0, b1);
                        else             { if (NB == 4) stage_half_off(B, k3, LB + 16384, tid, b2, b3); }
                    }
                }
                __builtin_amdgcn_s_barrier();
                if (p == 3) {
                    if (d == 0) {
                        if (st) { if (NB == 4) VMCNT(4); else VMCNT(2); }
                        else    VMCNT(0);
                    } else if (st) {
                        if (NB == 4) VMCNT(4); else VMCNT(2);
                    }
                }
                asm volatile("s_waitcnt lgkmcnt(0)" ::: "memory");
                __builtin_amdgcn_sched_barrier(0);
                __builtin_amdgcn_s_setprio(1);
#pragma unroll
                for (int i = 0; i < 2; ++i)
#pragma unroll
                    for (int n = 0; n < NB; ++n)
#pragma unroll
                        for (int ks = 0; ks < 2; ++ks)
                            acc[2 * p + i][n] = __builtin_amdgcn_mfma_f32_16x16x32_bf16(
                                af[i][ks], bf[n][ks], acc[2 * p + i][n], 0, 0, 0);
                __builtin_amdgcn_s_setprio(0);
                __builtin_amdgcn_s_barrier();
                __builtin_amdgcn_sched_barrier(0);
            }
        }
    }
}

// ---- dual-B core: BM=256, per-matrix frags NM (2 wide / 1 narrow) ----
template<int NM>
__device__ __forceinline__ void core_dual(
    const ushort* __restrict__ A, const ushort* __restrict__ B1,
    const ushort* __restrict__ B3,
    size_t a0, size_t a1, size_t a2, size_t a3,
    size_t b0, size_t b1,
    int K, char* lds, f32x4 (&acc1)[8][NM], f32x4 (&acc3)[8][NM], int tid)
{
    const int DB = 32768 + NM * 16384;
    int lane = tid & 63;
    int wid = tid >> 6;
    int wrow = wid >> 2, wcol = wid & 3;
    int l15 = lane & 15, hi = lane >> 4;

#pragma unroll
    for (int m = 0; m < 8; ++m)
#pragma unroll
        for (int n = 0; n < NM; ++n) {
            acc1[m][n] = (f32x4){0.f, 0.f, 0.f, 0.f};
            acc3[m][n] = (f32x4){0.f, 0.f, 0.f, 0.f};
        }

    int nj = K >> 7;

    stage_half_off(A, 0, lds + 0,     tid, a0, a1);
    stage_half_off(A, 0, lds + 16384, tid, a2, a3);
    stage_half_off(B1, 0, lds + 32768, tid, b0, b1);
    if (NM == 2) stage_half_off(B3, 0, lds + 32768 + 16384, tid, b0, b1);
    stage_half_off(B1, 64, lds + DB + 32768, tid, b0, b1);
    if (NM == 2) stage_half_off(B3, 64, lds + DB + 32768 + 16384, tid, b0, b1);
    if (NM == 2) VMCNT(4); else VMCNT(2);
    __builtin_amdgcn_s_barrier();
    __builtin_amdgcn_sched_barrier(0);

    for (int j = 0; j < nj; ++j) {
        int k1 = (2 * j + 1) << 6, k2 = (2 * j + 2) << 6, k3 = (2 * j + 3) << 6;
        bool st = (j < nj - 1);
#pragma unroll
        for (int d = 0; d < 2; ++d) {
            char* LA = lds + d * DB;
            char* LB = LA + 32768;
            char* LAo = lds + (d ^ 1) * DB;
            bf16x8 bf1[NM][2], bf3[NM][2];
#pragma unroll
            for (int p = 0; p < 4; ++p) {
                if (p == 0) {
#pragma unroll
                    for (int n = 0; n < NM; ++n)
#pragma unroll
                        for (int ks = 0; ks < 2; ++ks) {
                            int brow = wcol * (16 * NM) + n * 16 + l15;
                            bf1[n][ks] = ldfrag(LB, 0, brow,           ks * 64 + hi * 16);
                            bf3[n][ks] = ldfrag(LB, 0, brow + NM * 64, ks * 64 + hi * 16);
                        }
                }
                bf16x8 af[2][2];
#pragma unroll
                for (int i = 0; i < 2; ++i)
#pragma unroll
                    for (int ks = 0; ks < 2; ++ks)
                        af[i][ks] = ldfrag(LA, 0, wrow * 128 + (2 * p + i) * 16 + l15, ks * 64 + hi * 16);
                if (d == 0) {
                    if (p == 0)      stage_half_off(A, k1, LAo,         tid, a0, a1);
                    else if (p == 1) stage_half_off(A, k1, LAo + 16384, tid, a2, a3);
                    else if (p == 2) { if (st) stage_half_off(B1, k2, LB, tid, b0, b1); }
                    else             { if (st && NM == 2) stage_half_off(B3, k2, LB + 16384, tid, b0, b1); }
                } else {
                    if (st) {
                        if (p == 0)      stage_half_off(A, k2, LAo,         tid, a0, a1);
                        else if (p == 1) stage_half_off(A, k2, LAo + 16384, tid, a2, a3);
                        else if (p == 2) stage_half_off(B1, k3, LB, tid, b0, b1);
                        else             { if (NM == 2) stage_half_off(B3, k3, LB + 16384, tid, b0, b1); }
                    }
                }
                __builtin_amdgcn_s_barrier();
                if (p == 3) {
                    if (d == 0) {
                        if (st) { if (NM == 2) VMCNT(4); else VMCNT(2); }
                        else    VMCNT(0);
                    } else if (st) {
                        if (NM == 2) VMCNT(4); else VMCNT(2);
                    }
                }
                asm volatile("s_waitcnt lgkmcnt(0)" ::: "memory");
                __builtin_amdgcn_sched_barrier(0);
                __builtin_amdgcn_s_setprio(1);
#pragma unroll
                for (int i = 0; i < 2; ++i)
#pragma unroll
                    for (int n = 0; n < NM; ++n)
#pragma unroll
                        for (int ks = 0; ks < 2; ++ks) {
                            acc1[2 * p + i][n] = __builtin_amdgcn_mfma_f32_16x16x32_bf16(
                                af[i][ks], bf1[n][ks], acc1[2 * p + i][n], 0, 0, 0);
                            acc3[2 * p + i][n] = __builtin_amdgcn_mfma_f32_16x16x32_bf16(
                                af[i][ks], bf3[n][ks], acc3[2 * p + i][n], 0, 0, 0);
                        }
                __builtin_amdgcn_s_setprio(0);
                __builtin_amdgcn_s_barrier();
                __builtin_amdgcn_sched_barrier(0);
            }
        }
    }
}

// up-projection, fused SiLU: 512 blocks = 256 expert (wide) + 256 shared (narrow)
__global__ __launch_bounds__(512, 2) void gemm8_up(
    const ushort* __restrict__ xb,
    const ushort* __restrict__ w1T, const ushort* __restrict__ w3T,
    const ushort* __restrict__ sw1T, const ushort* __restrict__ sw3T,
    const int* __restrict__ assign_token,
    ushort* __restrict__ HH, const int* __restrict__ nvalid)
{
    __shared__ __align__(16) char lds[131072];
    int b = blockIdx.x;
    int tid = threadIdx.x;
    int rr = tid >> 3;
    int lane = tid & 63, wid = tid >> 6;
    int wrow = wid >> 2, wcol = wid & 3;

    if (b < 256) {
        int id = (b & 7) * 32 + (b >> 3);
        int e = id >> 4, rem = id & 15;
        int mt = rem >> 3, nt = rem & 7;
        int bm = mt * 256, bn = nt * 128;
        if (bm >= nvalid[e]) return;
        const int* at = assign_token + e * CAPE + bm;
        size_t a0 = (size_t)at[rr] * DIM;
        size_t a1 = (size_t)at[64 + rr] * DIM;
        size_t a2 = (size_t)at[128 + rr] * DIM;
        size_t a3 = (size_t)at[192 + rr] * DIM;
        const ushort* B1 = w1T + (size_t)e * HID * DIM;
        const ushort* B3 = w3T + (size_t)e * HID * DIM;
        size_t b0 = (size_t)(bn + rr) * DIM;
        size_t b1 = (size_t)(bn + 64 + rr) * DIM;
        f32x4 acc1[8][2], acc3[8][2];
        core_dual<2>(xb, B1, B3, a0, a1, a2, a3, b0, b1, DIM, lds, acc1, acc3, tid);
        ushort* O = HH + (size_t)e * CAPE * HID;
        int rbase = bm + wrow * 128 + (lane >> 4) * 4;
        int cbase = bn + wcol * 32 + (lane & 15);
#pragma unroll
        for (int m = 0; m < 8; ++m)
#pragma unroll
            for (int n = 0; n < 2; ++n) {
                int col = cbase + n * 16;
#pragma unroll
                for (int r = 0; r < 4; ++r) {
                    float g = acc1[m][n][r];
                    float s = g / (1.f + __expf(-g));
                    O[(size_t)(rbase + m * 16 + r) * HID + col] = f2bf(s * acc3[m][n][r]);
                }
            }
    } else {
        int b2 = b - 256;
        int id = (b2 & 7) * 32 + (b2 >> 3);
        int mt = id >> 4, nt = id & 15;
        int bm = mt * 256, bn = nt * 64;
        size_t a0 = (size_t)(bm + rr) * DIM;
        size_t a1 = (size_t)(bm + 64 + rr) * DIM;
        size_t a2 = (size_t)(bm + 128 + rr) * DIM;
        size_t a3 = (size_t)(bm + 192 + rr) * DIM;
        size_t b0 = (size_t)(bn + rr) * DIM;
        size_t b1 = (size_t)(sw3T - sw1T) + (size_t)(bn + rr) * DIM;
        f32x4 acc1[8][1], acc3[8][1];
        core_dual<1>(xb, sw1T, sw1T, a0, a1, a2, a3, b0, b1, DIM, lds, acc1, acc3, tid);
        ushort* O = HH + (size_t)NE * CAPE * HID;
        int rbase = bm + wrow * 128 + (lane >> 4) * 4;
        int col = bn + wcol * 16 + (lane & 15);
#pragma unroll
        for (int m = 0; m < 8; ++m)
#pragma unroll
            for (int r = 0; r < 4; ++r) {
                float g = acc1[m][0][r];
                float s = g / (1.f + __expf(-g));
                O[(size_t)(rbase + m * 16 + r) * HID + col] = f2bf(s * acc3[m][0][r]);
            }
    }
}

// down-projection: 512 blocks = 256 expert wide (-> ye bf16) + 256 shared narrow (-> mlpb bf16)
__global__ __launch_bounds__(512, 2) void gemm8_down(
    const ushort* __restrict__ HH, const ushort* __restrict__ w2T,
    const ushort* __restrict__ sw2T, ushort* __restrict__ ye,
    ushort* __restrict__ mlpb, const float* __restrict__ coefo,
    const int* __restrict__ nvalid)
{
    __shared__ __align__(16) char lds[131072];
    int b = blockIdx.x;
    int tid = threadIdx.x;
    int rr = tid >> 3;
    int lane = tid & 63, wid = tid >> 6;
    int wrow = wid >> 2, wcol = wid & 3;

    if (b < 256) {
        int id = (b & 7) * 32 + (b >> 3);
        int e = id >> 4, rem = id & 15;
        int mt = rem >> 3, nt = rem & 7;
        int bm = mt * 256, bn = nt * 256;
        if (bm >= nvalid[e]) return;
        const ushort* A = HH + (size_t)e * CAPE * HID;
        const ushort* B = w2T + (size_t)e * DIM * HID;
        ushort* Ob = ye + (size_t)e * CAPE * DIM;
        size_t a0 = (size_t)(bm + rr) * HID;
        size_t a1 = (size_t)(bm + 64 + rr) * HID;
        size_t a2 = (size_t)(bm + 128 + rr) * HID;
        size_t a3 = (size_t)(bm + 192 + rr) * HID;
        size_t b0 = (size_t)(bn + rr) * HID;
        size_t b1 = (size_t)(bn + 64 + rr) * HID;
        size_t b2 = (size_t)(bn + 128 + rr) * HID;
        size_t b3 = (size_t)(bn + 192 + rr) * HID;
        f32x4 acc[8][4];
        core_single<4>(A, B, a0, a1, a2, a3, b0, b1, b2, b3, HID, lds, acc, tid);
        int rbase = bm + wrow * 128 + (lane >> 4) * 4;
        int cbase = bn + wcol * 64 + (lane & 15);
#pragma unroll
        for (int m = 0; m < 8; ++m)
#pragma unroll
            for (int n = 0; n < 4; ++n) {
                int col = cbase + n * 16;
#pragma unroll
                for (int r = 0; r < 4; ++r)
                    Ob[(size_t)(rbase + m * 16 + r) * DIM + col] = f2bf(acc[m][n][r]);
            }
    } else {
        int b2i = b - 256;
        int id = (b2i & 7) * 32 + (b2i >> 3);
        int mt = id >> 4, nt = id & 15;
        int bm = mt * 256, bn = nt * 128;
        const ushort* A = HH + (size_t)NE * CAPE * HID;
        const ushort* B = sw2T;
        size_t a0 = (size_t)(bm + rr) * HID;
        size_t a1 = (size_t)(bm + 64 + rr) * HID;
        size_t a2 = (size_t)(bm + 128 + rr) * HID;
        size_t a3 = (size_t)(bm + 192 + rr) * HID;
        size_t b0 = (size_t)(bn + rr) * HID;
        size_t b1 = (size_t)(bn + 64 + rr) * HID;
        f32x4 acc[8][2];
        core_single<2>(A, B, a0, a1, a2, a3, b0, b1, 0, 0, HID, lds, acc, tid);
        int rbase = bm + wrow * 128 + (lane >> 4) * 4;
        int cbase = bn + wcol * 32 + (lane & 15);
#pragma unroll
        for (int m = 0; m < 8; ++m)
#pragma unroll
            for (int n = 0; n < 2; ++n) {
                int col = cbase + n * 16;
#pragma unroll
                for (int r = 0; r < 4; ++r) {
                    int row = rbase + m * 16 + r;
                    mlpb[(size_t)row * DIM + col] = f2bf(acc[m][n][r] * coefo[2 * row + 1]);
                }
            }
    }
}

// -------- final combine (pure write): out = mlp + coef0*(w0*ye[s0] + w1*ye[s1]) --------
__global__ __launch_bounds__(256) void combine_kernel(
    const ushort* __restrict__ ye, const ushort* __restrict__ mlpb,
    const int* __restrict__ sidx, const float* __restrict__ swt,
    const float* __restrict__ coefo, float* __restrict__ out)
{
    int idx = blockIdx.x * 256 + threadIdx.x;
    int t = idx >> 9;
    int d = (idx & 511) << 2;
    int s0 = sidx[t * 2], s1 = sidx[t * 2 + 1];
    float c0 = coefo[t * 2];
    float w0 = swt[t * 2] * c0, w1 = swt[t * 2 + 1] * c0;
    uint2 mb = *(const uint2*)(mlpb + (size_t)t * DIM + d);
    const ushort* mp = (const ushort*)&mb;
    float4 v;
    v.x = bf2f(mp[0]); v.y = bf2f(mp[1]); v.z = bf2f(mp[2]); v.w = bf2f(mp[3]);
    if (s0 >= 0) {
        uint2 y = *(const uint2*)(ye + (size_t)s0 * DIM + d);
        const ushort* yp = (const ushort*)&y;
        v.x += w0 * bf2f(yp[0]); v.y += w0 * bf2f(yp[1]);
        v.z += w0 * bf2f(yp[2]); v.w += w0 * bf2f(yp[3]);
    }
    if (s1 >= 0) {
        uint2 y = *(const uint2*)(ye + (size_t)s1 * DIM + d);
        const ushort* yp = (const ushort*)&y;
        v.x += w1 * bf2f(yp[0]); v.y += w1 * bf2f(yp[1]);
        v.z += w1 * bf2f(yp[2]); v.w += w1 * bf2f(yp[3]);
    }
    *(float4*)(out + (size_t)t * DIM + d) = v;
}

extern "C" void kernel_launch(void* const* d_in, const int* in_sizes, int n_in,
                              void* d_out, int out_size, void* d_ws, size_t ws_size,
                              hipStream_t stream)
{
    const float* x      = (const float*)d_in[0];
    const float* gate_w = (const float*)d_in[1];
    const float* w1     = (const float*)d_in[2];
    const float* w3     = (const float*)d_in[3];
    const float* w2     = (const float*)d_in[4];
    const float* sw1    = (const float*)d_in[5];
    const float* sw3    = (const float*)d_in[6];
    const float* sw2    = (const float*)d_in[7];
    const float* coef_w = (const float*)d_in[8];
    const float* coef_b = (const float*)d_in[9];
    float* out = (float*)d_out;

    char* ws = (char*)d_ws;
    size_t off = 0;
    auto alloc = [&](size_t bytes) -> void* {
        void* p = ws + off;
        off += (bytes + 255) & ~(size_t)255;
        return p;
    };
    int*    nvalid       = (int*)alloc(NE * 4);
    int*    topidx       = (int*)alloc((size_t)T_TOK * 2 * 4);
    float*  gatesw       = (float*)alloc((size_t)T_TOK * 2 * 4);
    float*  coefo        = (float*)alloc((size_t)T_TOK * 2 * 4);
    int*    sidx         = (int*)alloc((size_t)T_TOK * 2 * 4);
    float*  swt          = (float*)alloc((size_t)T_TOK * 2 * 4);
    int*    assign_token = (int*)alloc((size_t)NE * CAPE * 4);
    float*  probs_part   = (float*)alloc((size_t)256 * NE * 4);
    ushort* w1T  = (ushort*)alloc((size_t)NE * HID * DIM * 2);
    ushort* w3T  = (ushort*)alloc((size_t)NE * HID * DIM * 2);
    ushort* w2T  = (ushort*)alloc((size_t)NE * DIM * HID * 2);
    ushort* sw1T = (ushort*)alloc((size_t)HID * DIM * 2);
    ushort* sw3T = (ushort*)alloc((size_t)HID * DIM * 2);
    ushort* sw2T = (ushort*)alloc((size_t)DIM * HID * 2);
    ushort* xb   = (ushort*)alloc((size_t)T_TOK * DIM * 2);
    size_t HROWS = (size_t)NE * CAPE + T_TOK;
    ushort* HH   = (ushort*)alloc(HROWS * HID * 2);
    ushort* ye   = (ushort*)alloc((size_t)NE * CAPE * DIM * 2);
    ushort* mlpb = (ushort*)alloc((size_t)T_TOK * DIM * 2);

    float* out_tail = out + (size_t)T_TOK * DIM;

    // 1: logits + convert + fused finish (zeroes l_aux)
    logits_kernel<<<T_TOK / 16, 256, 0, stream>>>(
        x, gate_w, coef_w, coef_b, xb, topidx, gatesw, coefo, probs_part, out_tail);
    // 2: scan (16 blocks) overlapped with all weight transposes (3264 blocks)
    scan_transpose<<<NE + 3264, 256, 0, stream>>>(
        topidx, gatesw, probs_part, sidx, swt, assign_token, nvalid, out_tail,
        w1, w3, w2, sw1, sw3, sw2, w1T, w3T, w2T, sw1T, sw3T, sw2T);
    // 3: 8-phase up-projection with fused SiLU
    gemm8_up<<<512, 512, 0, stream>>>(xb, w1T, w3T, sw1T, sw3T, assign_token, HH, nvalid);
    // 4: 8-phase down-projection (expert -> ye, shared -> mlpb)
    gemm8_down<<<512, 512, 0, stream>>>(HH, w2T, sw2T, ye, mlpb, coefo, nvalid);
    // 5: pure-write combine
    combine_kernel<<<(T_TOK * (DIM / 4)) / 256, 256, 0, stream>>>(
        ye, mlpb, sidx, swt, coefo, out);
}

// Round 16
// 390.896 us; speedup vs baseline: 1.0307x; 1.0246x over previous
//
#include <hip/hip_runtime.h>
#include <hip/hip_bf16.h>
#include <stdint.h>

#define T_TOK 4096
#define DIM   2048
#define HID   1024
#define NE    16
#define CAPE  512

typedef __bf16 bf16x8 __attribute__((ext_vector_type(8)));
typedef float  f32x4  __attribute__((ext_vector_type(4)));

__device__ __forceinline__ ushort f2bf(float f) {
    union { float f; uint32_t u; } v; v.f = f;
    uint32_t r = (v.u + 0x7FFFu + ((v.u >> 16) & 1u)) >> 16;
    return (ushort)r;
}
__device__ __forceinline__ float bf2f(ushort u) {
    union { uint32_t u; float f; } v; v.u = (uint32_t)u << 16; return v.f;
}
__device__ __forceinline__ void gload16(const void* g, void* lds) {
    __builtin_amdgcn_global_load_lds(
        (const __attribute__((address_space(1))) uint32_t*)g,
        (__attribute__((address_space(3))) uint32_t*)lds, 16, 0, 0);
}
#define VMCNT(n) asm volatile("s_waitcnt vmcnt(" #n ")" ::: "memory")

// ------ logits + x->bf16 convert + FUSED finish: 16 tokens/block ------
__global__ __launch_bounds__(256) void logits_kernel(
    const float* __restrict__ x, const float* __restrict__ gate_w,
    const float* __restrict__ coef_w, const float* __restrict__ coef_b,
    ushort* __restrict__ xb,
    int* __restrict__ topidx, float* __restrict__ gatesw,
    float* __restrict__ coefo, float* __restrict__ probs_part,
    float* __restrict__ laux)
{
    __shared__ float gws[18 * 512];
    __shared__ float wred[4][NE];
    int tid = threadIdx.x;
    int wv = tid >> 6, lane = tid & 63;
    int tbase = blockIdx.x * 16 + wv * 4;
    float acc[4][18];
#pragma unroll
    for (int tk = 0; tk < 4; ++tk)
#pragma unroll
        for (int o = 0; o < 18; ++o) acc[tk][o] = 0.f;

    for (int c = 0; c < 4; ++c) {
        int d0 = c * 512;
        __syncthreads();
        const float4* g4 = (const float4*)(gate_w + (size_t)d0 * NE);
        for (int i = tid; i < 2048; i += 256) {
            float4 v = g4[i];
            int dd = i >> 2, o0 = (i & 3) * 4;
            gws[(o0 + 0) * 512 + dd] = v.x;
            gws[(o0 + 1) * 512 + dd] = v.y;
            gws[(o0 + 2) * 512 + dd] = v.z;
            gws[(o0 + 3) * 512 + dd] = v.w;
        }
        for (int i = tid; i < 1024; i += 256) {
            float v = coef_w[(size_t)d0 * 2 + i];
            gws[(16 + (i & 1)) * 512 + (i >> 1)] = v;
        }
        __syncthreads();
#pragma unroll
        for (int tk = 0; tk < 4; ++tk) {
            int t = tbase + tk;
            const float* xr = x + (size_t)t * DIM + d0;
            float xv[8];
#pragma unroll
            for (int j = 0; j < 8; ++j) xv[j] = xr[j * 64 + lane];
#pragma unroll
            for (int j = 0; j < 8; ++j)
                xb[(size_t)t * DIM + d0 + j * 64 + lane] = f2bf(xv[j]);
#pragma unroll
            for (int o = 0; o < 18; ++o) {
                const float* gr = &gws[o * 512 + lane];
                float a = acc[tk][o];
#pragma unroll
                for (int j = 0; j < 8; ++j) a += xv[j] * gr[j * 64];
                acc[tk][o] = a;
            }
        }
    }
#pragma unroll
    for (int tk = 0; tk < 4; ++tk)
#pragma unroll
        for (int off = 32; off > 0; off >>= 1)
#pragma unroll
            for (int o = 0; o < 18; ++o)
                acc[tk][o] += __shfl_down(acc[tk][o], off, 64);

    if (lane == 0) {
        float ps[NE];
#pragma unroll
        for (int e = 0; e < NE; ++e) ps[e] = 0.f;
#pragma unroll
        for (int tk = 0; tk < 4; ++tk) {
            int t = tbase + tk;
            float lg[18];
#pragma unroll
            for (int o = 0; o < 18; ++o) lg[o] = acc[tk][o];
            float m = lg[0];
#pragma unroll
            for (int e = 1; e < NE; ++e) m = fmaxf(m, lg[e]);
            float p[NE];
            float ssum = 0.f;
#pragma unroll
            for (int e = 0; e < NE; ++e) { p[e] = expf(lg[e] - m); ssum += p[e]; }
            float inv = 1.f / ssum;
#pragma unroll
            for (int e = 0; e < NE; ++e) p[e] *= inv;
            int i1 = 0;
#pragma unroll
            for (int e = 1; e < NE; ++e) if (p[e] > p[i1]) i1 = e;
            int i2 = -1;
#pragma unroll
            for (int e = 0; e < NE; ++e) { if (e == i1) continue; if (i2 < 0 || p[e] > p[i2]) i2 = e; }
            float g0 = p[i1], g1 = p[i2], gs = g0 + g1;
            topidx[t * 2 + 0] = i1; topidx[t * 2 + 1] = i2;
            gatesw[t * 2 + 0] = g0 / gs; gatesw[t * 2 + 1] = g1 / gs;
            float c0 = lg[16] + coef_b[0], c1 = lg[17] + coef_b[1];
            float cm = fmaxf(c0, c1);
            float e0 = expf(c0 - cm), e1 = expf(c1 - cm);
            float cs = e0 + e1;
            coefo[t * 2 + 0] = e0 / cs; coefo[t * 2 + 1] = e1 / cs;
#pragma unroll
            for (int e = 0; e < NE; ++e) ps[e] += p[e];
        }
#pragma unroll
        for (int e = 0; e < NE; ++e) wred[wv][e] = ps[e];
    }
    __syncthreads();
    if (tid < NE)
        probs_part[blockIdx.x * NE + tid] =
            wred[0][tid] + wred[1][tid] + wred[2][tid] + wred[3][tid];
    if (blockIdx.x == 0 && tid == 0) laux[0] = 0.f;
}

// ==== merged scan (blocks 0..15) + weight transposes (w1,w3,sw1,sw3,sw2) ====
__global__ __launch_bounds__(256) void scan_transpose(
    const int* __restrict__ topidx, const float* __restrict__ gatesw,
    const float* __restrict__ probs_part,
    int* __restrict__ sidx, float* __restrict__ swt,
    int* __restrict__ assign_token, int* __restrict__ nvalid,
    float* __restrict__ out_tail,
    const float* __restrict__ w1, const float* __restrict__ w3,
    const float* __restrict__ sw1, const float* __restrict__ sw3,
    const float* __restrict__ sw2,
    ushort* __restrict__ w1T, ushort* __restrict__ w3T,
    ushort* __restrict__ sw1T, ushort* __restrict__ sw3T, ushort* __restrict__ sw2T)
{
    __shared__ __align__(16) ushort tile[128][264];
    int tid = threadIdx.x;

    if (blockIdx.x < NE) {
        __shared__ int wcnt[4];
        __shared__ float fred[4];
        __shared__ int runs;
        __shared__ int cnt0s;
        int e = blockIdx.x;
        int wv = tid >> 6, ln = tid & 63;
        unsigned long long ltmask = (1ull << ln) - 1ull;
        if (tid == 0) runs = 0;
        __syncthreads();
        for (int kk = 0; kk < 2; ++kk) {
            for (int c = 0; c < T_TOK; c += 256) {
                int t = c + tid;
                bool m = (topidx[t * 2 + kk] == e);
                unsigned long long b = __ballot(m);
                int within = __popcll(b & ltmask);
                if (ln == 0) wcnt[wv] = __popcll(b);
                __syncthreads();
                int cross = 0;
                for (int w = 0; w < wv; ++w) cross += wcnt[w];
                int pos = runs + cross + within;
                if (m) {
                    bool keep = pos < CAPE;
                    sidx[t * 2 + kk] = keep ? (e * CAPE + pos) : -1;
                    swt[t * 2 + kk] = keep ? gatesw[t * 2 + kk] : 0.f;
                    if (keep) assign_token[e * CAPE + pos] = t;
                }
                __syncthreads();
                if (tid == 0) runs += wcnt[0] + wcnt[1] + wcnt[2] + wcnt[3];
                __syncthreads();
            }
            if (kk == 0 && tid == 0) cnt0s = runs;
            __syncthreads();
        }
        for (int p = runs + tid; p < CAPE; p += 256)
            assign_token[e * CAPE + p] = 0;
        float val = probs_part[tid * NE + e];
#pragma unroll
        for (int off = 32; off > 0; off >>= 1) val += __shfl_down(val, off, 64);
        if (ln == 0) fred[wv] = val;
        __syncthreads();
        if (tid == 0) {
            float psum = fred[0] + fred[1] + fred[2] + fred[3];
            int total = runs;
            nvalid[e] = min(CAPE, total);
            out_tail[1 + e] = (float)total;
            float term = (psum / (float)T_TOK) * ((float)cnt0s / (float)T_TOK) * (float)NE;
            atomicAdd(&out_tail[0], term);
        }
        return;
    }

    int id = blockIdx.x - NE;
    const float* in; ushort* outp; int R, C, tx, ty;
    if (id < 2048) {
        int seg = id >> 10;          // 0:w1 1:w3 (1024 tiles each)
        int rem = id & 1023;
        int e = rem >> 6;
        int r2 = rem & 63;
        R = DIM; C = HID; tx = r2 & 7; ty = r2 >> 3;
        in   = (seg ? w3 : w1) + (size_t)e * DIM * HID;
        outp = (seg ? w3T : w1T) + (size_t)e * HID * DIM;
    } else {
        int id2 = id - 2048;
        int seg = id2 >> 6;          // 0:sw1 1:sw3 2:sw2
        int r2 = id2 & 63;
        if (seg < 2) {
            R = DIM; C = HID; tx = r2 & 7; ty = r2 >> 3;
            in = seg ? sw3 : sw1; outp = seg ? sw3T : sw1T;
        } else {
            R = HID; C = DIM; tx = r2 & 3; ty = r2 >> 2;
            in = sw2; outp = sw2T;
        }
    }
    int r0 = tx * 256, c0 = ty * 128;
    int t31 = tid & 31, t8 = tid >> 5;

#pragma unroll
    for (int it = 0; it < 8; ++it) {
        int r4 = (it * 8 + t8) * 4;
        int c4 = t31 * 4;
        const float* ip = in + (size_t)(r0 + r4) * C + c0 + c4;
        float va[4][4];
        *(float4*)va[0] = *(const float4*)(ip);
        *(float4*)va[1] = *(const float4*)(ip + C);
        *(float4*)va[2] = *(const float4*)(ip + 2 * (size_t)C);
        *(float4*)va[3] = *(const float4*)(ip + 3 * (size_t)C);
#pragma unroll
        for (int j = 0; j < 4; ++j) {
            uint2 u;
            u.x = (uint32_t)f2bf(va[0][j]) | ((uint32_t)f2bf(va[1][j]) << 16);
            u.y = (uint32_t)f2bf(va[2][j]) | ((uint32_t)f2bf(va[3][j]) << 16);
            *(uint2*)&tile[c4 + j][r4] = u;
        }
    }
    __syncthreads();

#pragma unroll
    for (int it = 0; it < 16; ++it) {
        int c = it * 8 + t8;
        int k = t31 * 8;
        uint4 o = *(const uint4*)&tile[c][k];
        *(uint4*)(outp + (size_t)(c0 + c) * R + r0 + k) = o;
    }
}

// ================= GEMM cores =================
__device__ __forceinline__ void stage_half_off(
    const ushort* __restrict__ G, int k0, char* region, int tid,
    size_t off0, size_t off1)
{
#pragma unroll
    for (int q = 0; q < 2; ++q) {
        int c = q * 512 + tid;
        int row = c >> 3;
        int cb = (c & 7) << 4;
        int scb = cb ^ ((row & 7) << 4);
        const ushort* src = G + (q ? off1 : off0) + k0 + (scb >> 1);
        gload16(src, region + ((c - (tid & 63)) << 4));
    }
}

__device__ __forceinline__ bf16x8 ldfrag(const char* lds, int region, int row, int cb) {
    return *(const bf16x8*)(lds + region + row * 128 + (cb ^ ((row & 7) << 4)));
}

// ---- 8-phase single-B core (shared down path, NB=2) ----
template<int NB>
__device__ __forceinline__ void core_single(
    const ushort* __restrict__ A, const ushort* __restrict__ B,
    size_t a0, size_t a1, size_t a2, size_t a3,
    size_t b0, size_t b1, size_t b2, size_t b3,
    int K, char* lds, f32x4 (&acc)[8][NB], int tid)
{
    const int DB = 32768 + NB * 8192;
    int lane = tid & 63;
    int wid = tid >> 6;
    int wrow = wid >> 2, wcol = wid & 3;
    int l15 = lane & 15, hi = lane >> 4;

#pragma unroll
    for (int m = 0; m < 8; ++m)
#pragma unroll
        for (int n = 0; n < NB; ++n)
            acc[m][n] = (f32x4){0.f, 0.f, 0.f, 0.f};

    int nj = K >> 7;

    stage_half_off(A, 0, lds + 0,           tid, a0, a1);
    stage_half_off(A, 0, lds + 16384,       tid, a2, a3);
    stage_half_off(B, 0, lds + 32768,       tid, b0, b1);
    if (NB == 4) stage_half_off(B, 0, lds + 32768 + 16384, tid, b2, b3);
    stage_half_off(B, 64, lds + DB + 32768, tid, b0, b1);
    if (NB == 4) stage_half_off(B, 64, lds + DB + 32768 + 16384, tid, b2, b3);
    if (NB == 4) VMCNT(4); else VMCNT(2);
    __builtin_amdgcn_s_barrier();
    __builtin_amdgcn_sched_barrier(0);

    for (int j = 0; j < nj; ++j) {
        int k1 = (2 * j + 1) << 6, k2 = (2 * j + 2) << 6, k3 = (2 * j + 3) << 6;
        bool st = (j < nj - 1);
#pragma unroll
        for (int d = 0; d < 2; ++d) {
            char* LA = lds + d * DB;
            char* LB = LA + 32768;
            char* LAo = lds + (d ^ 1) * DB;
            bf16x8 bf[NB][2];
#pragma unroll
            for (int p = 0; p < 4; ++p) {
                if (p == 0) {
#pragma unroll
                    for (int n = 0; n < NB; ++n)
#pragma unroll
                        for (int ks = 0; ks < 2; ++ks)
                            bf[n][ks] = ldfrag(LB, 0, wcol * (16 * NB) + n * 16 + l15, ks * 64 + hi * 16);
                }
                bf16x8 af[2][2];
#pragma unroll
                for (int i = 0; i < 2; ++i)
#pragma unroll
                    for (int ks = 0; ks < 2; ++ks)
                        af[i][ks] = ldfrag(LA, 0, wrow * 128 + (2 * p + i) * 16 + l15, ks * 64 + hi * 16);
                if (d == 0) {
                    if (p == 0)      stage_half_off(A, k1, LAo,         tid, a0, a1);
                    else if (p == 1) stage_half_off(A, k1, LAo + 16384, tid, a2, a3);
                    else if (p == 2) { if (st) stage_half_off(B, k2, LB, tid, b0, b1); }
                    else             { if (st && NB == 4) stage_half_off(B, k2, LB + 16384, tid, b2, b3); }
                } else {
                    if (st) {
                        if (p == 0)      stage_half_off(A, k2, LAo,         tid, a0, a1);
                        else if (p == 1) stage_half_off(A, k2, LAo + 16384, tid, a2, a3);
                        else if (p == 2) stage_half_off(B, k3, LB, tid, b0, b1);
                        else             { if (NB == 4) stage_half_off(B, k3, LB + 16384, tid, b2, b3); }
                    }
                }
                __builtin_amdgcn_s_barrier();
                if (p == 3) {
                    if (d == 0) {
                        if (st) { if (NB == 4) VMCNT(4); else VMCNT(2); }
                        else    VMCNT(0);
                    } else if (st) {
                        if (NB == 4) VMCNT(4); else VMCNT(2);
                    }
                }
                asm volatile("s_waitcnt lgkmcnt(0)" ::: "memory");
                __builtin_amdgcn_sched_barrier(0);
                __builtin_amdgcn_s_setprio(1);
#pragma unroll
                for (int i = 0; i < 2; ++i)
#pragma unroll
                    for (int n = 0; n < NB; ++n)
#pragma unroll
                        for (int ks = 0; ks < 2; ++ks)
                            acc[2 * p + i][n] = __builtin_amdgcn_mfma_f32_16x16x32_bf16(
                                af[i][ks], bf[n][ks], acc[2 * p + i][n], 0, 0, 0);
                __builtin_amdgcn_s_setprio(0);
                __builtin_amdgcn_s_barrier();
                __builtin_amdgcn_sched_barrier(0);
            }
        }
    }
}

// ---- 8-phase dual-B core (up path) ----
template<int NM>
__device__ __forceinline__ void core_dual(
    const ushort* __restrict__ A, const ushort* __restrict__ B1,
    const ushort* __restrict__ B3,
    size_t a0, size_t a1, size_t a2, size_t a3,
    size_t b0, size_t b1,
    int K, char* lds, f32x4 (&acc1)[8][NM], f32x4 (&acc3)[8][NM], int tid)
{
    const int DB = 32768 + NM * 16384;
    int lane = tid & 63;
    int wid = tid >> 6;
    int wrow = wid >> 2, wcol = wid & 3;
    int l15 = lane & 15, hi = lane >> 4;

#pragma unroll
    for (int m = 0; m < 8; ++m)
#pragma unroll
        for (int n = 0; n < NM; ++n) {
            acc1[m][n] = (f32x4){0.f, 0.f, 0.f, 0.f};
            acc3[m][n] = (f32x4){0.f, 0.f, 0.f, 0.f};
        }

    int nj = K >> 7;

    stage_half_off(A, 0, lds + 0,     tid, a0, a1);
    stage_half_off(A, 0, lds + 16384, tid, a2, a3);
    stage_half_off(B1, 0, lds + 32768, tid, b0, b1);
    if (NM == 2) stage_half_off(B3, 0, lds + 32768 + 16384, tid, b0, b1);
    stage_half_off(B1, 64, lds + DB + 32768, tid, b0, b1);
    if (NM == 2) stage_half_off(B3, 64, lds + DB + 32768 + 16384, tid, b0, b1);
    if (NM == 2) VMCNT(4); else VMCNT(2);
    __builtin_amdgcn_s_barrier();
    __builtin_amdgcn_sched_barrier(0);

    for (int j = 0; j < nj; ++j) {
        int k1 = (2 * j + 1) << 6, k2 = (2 * j + 2) << 6, k3 = (2 * j + 3) << 6;
        bool st = (j < nj - 1);
#pragma unroll
        for (int d = 0; d < 2; ++d) {
            char* LA = lds + d * DB;
            char* LB = LA + 32768;
            char* LAo = lds + (d ^ 1) * DB;
            bf16x8 bf1[NM][2], bf3[NM][2];
#pragma unroll
            for (int p = 0; p < 4; ++p) {
                if (p == 0) {
#pragma unroll
                    for (int n = 0; n < NM; ++n)
#pragma unroll
                        for (int ks = 0; ks < 2; ++ks) {
                            int brow = wcol * (16 * NM) + n * 16 + l15;
                            bf1[n][ks] = ldfrag(LB, 0, brow,           ks * 64 + hi * 16);
                            bf3[n][ks] = ldfrag(LB, 0, brow + NM * 64, ks * 64 + hi * 16);
                        }
                }
                bf16x8 af[2][2];
#pragma unroll
                for (int i = 0; i < 2; ++i)
#pragma unroll
                    for (int ks = 0; ks < 2; ++ks)
                        af[i][ks] = ldfrag(LA, 0, wrow * 128 + (2 * p + i) * 16 + l15, ks * 64 + hi * 16);
                if (d == 0) {
                    if (p == 0)      stage_half_off(A, k1, LAo,         tid, a0, a1);
                    else if (p == 1) stage_half_off(A, k1, LAo + 16384, tid, a2, a3);
                    else if (p == 2) { if (st) stage_half_off(B1, k2, LB, tid, b0, b1); }
                    else             { if (st && NM == 2) stage_half_off(B3, k2, LB + 16384, tid, b0, b1); }
                } else {
                    if (st) {
                        if (p == 0)      stage_half_off(A, k2, LAo,         tid, a0, a1);
                        else if (p == 1) stage_half_off(A, k2, LAo + 16384, tid, a2, a3);
                        else if (p == 2) stage_half_off(B1, k3, LB, tid, b0, b1);
                        else             { if (NM == 2) stage_half_off(B3, k3, LB + 16384, tid, b0, b1); }
                    }
                }
                __builtin_amdgcn_s_barrier();
                if (p == 3) {
                    if (d == 0) {
                        if (st) { if (NM == 2) VMCNT(4); else VMCNT(2); }
                        else    VMCNT(0);
                    } else if (st) {
                        if (NM == 2) VMCNT(4); else VMCNT(2);
                    }
                }
                asm volatile("s_waitcnt lgkmcnt(0)" ::: "memory");
                __builtin_amdgcn_sched_barrier(0);
                __builtin_amdgcn_s_setprio(1);
#pragma unroll
                for (int i = 0; i < 2; ++i)
#pragma unroll
                    for (int n = 0; n < NM; ++n)
#pragma unroll
                        for (int ks = 0; ks < 2; ++ks) {
                            acc1[2 * p + i][n] = __builtin_amdgcn_mfma_f32_16x16x32_bf16(
                                af[i][ks], bf1[n][ks], acc1[2 * p + i][n], 0, 0, 0);
                            acc3[2 * p + i][n] = __builtin_amdgcn_mfma_f32_16x16x32_bf16(
                                af[i][ks], bf3[n][ks], acc3[2 * p + i][n], 0, 0, 0);
                        }
                __builtin_amdgcn_s_setprio(0);
                __builtin_amdgcn_s_barrier();
                __builtin_amdgcn_sched_barrier(0);
            }
        }
    }
}

// up-projection, fused SiLU: 512 blocks = 256 expert (wide) + 256 shared (narrow)
__global__ __launch_bounds__(512, 2) void gemm8_up(
    const ushort* __restrict__ xb,
    const ushort* __restrict__ w1T, const ushort* __restrict__ w3T,
    const ushort* __restrict__ sw1T, const ushort* __restrict__ sw3T,
    const int* __restrict__ assign_token,
    ushort* __restrict__ HH, const int* __restrict__ nvalid)
{
    __shared__ __align__(16) char lds[131072];
    int b = blockIdx.x;
    int tid = threadIdx.x;
    int rr = tid >> 3;
    int lane = tid & 63, wid = tid >> 6;
    int wrow = wid >> 2, wcol = wid & 3;

    if (b < 256) {
        int id = (b & 7) * 32 + (b >> 3);
        int e = id >> 4, rem = id & 15;
        int mt = rem >> 3, nt = rem & 7;
        int bm = mt * 256, bn = nt * 128;
        if (bm >= nvalid[e]) return;
        const int* at = assign_token + e * CAPE + bm;
        size_t a0 = (size_t)at[rr] * DIM;
        size_t a1 = (size_t)at[64 + rr] * DIM;
        size_t a2 = (size_t)at[128 + rr] * DIM;
        size_t a3 = (size_t)at[192 + rr] * DIM;
        const ushort* B1 = w1T + (size_t)e * HID * DIM;
        const ushort* B3 = w3T + (size_t)e * HID * DIM;
        size_t b0 = (size_t)(bn + rr) * DIM;
        size_t b1 = (size_t)(bn + 64 + rr) * DIM;
        f32x4 acc1[8][2], acc3[8][2];
        core_dual<2>(xb, B1, B3, a0, a1, a2, a3, b0, b1, DIM, lds, acc1, acc3, tid);
        ushort* O = HH + (size_t)e * CAPE * HID;
        int rbase = bm + wrow * 128 + (lane >> 4) * 4;
        int cbase = bn + wcol * 32 + (lane & 15);
#pragma unroll
        for (int m = 0; m < 8; ++m)
#pragma unroll
            for (int n = 0; n < 2; ++n) {
                int col = cbase + n * 16;
#pragma unroll
                for (int r = 0; r < 4; ++r) {
                    float g = acc1[m][n][r];
                    float s = g / (1.f + __expf(-g));
                    O[(size_t)(rbase + m * 16 + r) * HID + col] = f2bf(s * acc3[m][n][r]);
                }
            }
    } else {
        int b2 = b - 256;
        int id = (b2 & 7) * 32 + (b2 >> 3);
        int mt = id >> 4, nt = id & 15;
        int bm = mt * 256, bn = nt * 64;
        size_t a0 = (size_t)(bm + rr) * DIM;
        size_t a1 = (size_t)(bm + 64 + rr) * DIM;
        size_t a2 = (size_t)(bm + 128 + rr) * DIM;
        size_t a3 = (size_t)(bm + 192 + rr) * DIM;
        size_t b0 = (size_t)(bn + rr) * DIM;
        size_t b1 = (size_t)(sw3T - sw1T) + (size_t)(bn + rr) * DIM;
        f32x4 acc1[8][1], acc3[8][1];
        core_dual<1>(xb, sw1T, sw1T, a0, a1, a2, a3, b0, b1, DIM, lds, acc1, acc3, tid);
        ushort* O = HH + (size_t)NE * CAPE * HID;
        int rbase = bm + wrow * 128 + (lane >> 4) * 4;
        int col = bn + wcol * 16 + (lane & 15);
#pragma unroll
        for (int m = 0; m < 8; ++m)
#pragma unroll
            for (int r = 0; r < 4; ++r) {
                float g = acc1[m][0][r];
                float s = g / (1.f + __expf(-g));
                O[(size_t)(rbase + m * 16 + r) * HID + col] = f2bf(s * acc3[m][0][r]);
            }
    }
}

// down-projection: 512 blocks.
// blocks [0,256): expert, 2-phase dbuf, B = raw f32 w2 [K][N] reg-staged
//                 (convert + micro-transpose into swizzled LDS), -> ye bf16
// blocks [256,512): shared, 8-phase on sw2T -> mlpb bf16
__global__ __launch_bounds__(512, 2) void gemm8_down(
    const ushort* __restrict__ HH, const float* __restrict__ w2f,
    const ushort* __restrict__ sw2T, ushort* __restrict__ ye,
    ushort* __restrict__ mlpb, const float* __restrict__ coefo,
    const int* __restrict__ nvalid)
{
    __shared__ __align__(16) char lds[131072];
    int b = blockIdx.x;
    int tid = threadIdx.x;
    int rr = tid >> 3;
    int lane = tid & 63, wid = tid >> 6;
    int wrow = wid >> 2, wcol = wid & 3;

    if (b < 256) {
        int id = (b & 7) * 32 + (b >> 3);
        int e = id >> 4, rem = id & 15;
        int mt = rem >> 3, nt = rem & 7;
        int bm = mt * 256, bn = nt * 256;
        if (bm >= nvalid[e]) return;
        const ushort* A = HH + (size_t)e * CAPE * HID;
        const float*  W = w2f + (size_t)e * HID * DIM;
        ushort* Ob = ye + (size_t)e * CAPE * DIM;
        size_t a0 = (size_t)(bm + rr) * HID;
        size_t a1 = (size_t)(bm + 64 + rr) * HID;
        size_t a2 = (size_t)(bm + 128 + rr) * HID;
        size_t a3 = (size_t)(bm + 192 + rr) * HID;
        int nq = tid & 63;           // n-group: rows r = nq*4+j
        int kb = (tid >> 6) * 8;     // k-base within tile
        int l15 = lane & 15, hi = lane >> 4;

        f32x4 acc[8][4];
#pragma unroll
        for (int m = 0; m < 8; ++m)
#pragma unroll
            for (int n = 0; n < 4; ++n)
                acc[m][n] = (f32x4){0.f, 0.f, 0.f, 0.f};

        float4 breg[8];
        // prologue: tile 0 -> dbuf 0
        stage_half_off(A, 0, lds + 0,     tid, a0, a1);
        stage_half_off(A, 0, lds + 16384, tid, a2, a3);
        {
            const float* src = W + (size_t)kb * DIM + bn + nq * 4;
#pragma unroll
            for (int kk = 0; kk < 8; ++kk)
                breg[kk] = *(const float4*)(src + (size_t)kk * DIM);
        }
        {
            char* LB = lds + 32768;
#pragma unroll
            for (int j = 0; j < 4; ++j) {
                int r = nq * 4 + j;
                ushort pk[8];
#pragma unroll
                for (int kk = 0; kk < 8; ++kk) pk[kk] = f2bf(((const float*)&breg[kk])[j]);
                int cb = (kb * 2) ^ ((r & 7) << 4);
                *(uint4*)(LB + r * 128 + cb) = *(uint4*)pk;
            }
        }
        VMCNT(0);
        __syncthreads();

        int d = 0;
        for (int t = 0; t < HID / 64; ++t) {
            bool pf = (t < HID / 64 - 1);
            char* LA = lds + d * 65536;
            char* LB = LA + 32768;
            char* LAo = lds + (d ^ 1) * 65536;
            char* LBo = LAo + 32768;
            if (pf) {
                int k0 = (t + 1) * 64;
                stage_half_off(A, k0, LAo,         tid, a0, a1);
                stage_half_off(A, k0, LAo + 16384, tid, a2, a3);
                const float* src = W + (size_t)(k0 + kb) * DIM + bn + nq * 4;
#pragma unroll
                for (int kk = 0; kk < 8; ++kk)
                    breg[kk] = *(const float4*)(src + (size_t)kk * DIM);
            }
            // compute current tile
#pragma unroll
            for (int ks = 0; ks < 2; ++ks) {
                bf16x8 af[8], bf[4];
#pragma unroll
                for (int m = 0; m < 8; ++m)
                    af[m] = ldfrag(LA, 0, wrow * 128 + m * 16 + l15, ks * 64 + hi * 16);
#pragma unroll
                for (int n = 0; n < 4; ++n)
                    bf[n] = ldfrag(LB, 0, wcol * 64 + n * 16 + l15, ks * 64 + hi * 16);
#pragma unroll
                for (int m = 0; m < 8; ++m)
#pragma unroll
                    for (int n = 0; n < 4; ++n)
                        acc[m][n] = __builtin_amdgcn_mfma_f32_16x16x32_bf16(
                            af[m], bf[n], acc[m][n], 0, 0, 0);
            }
            if (pf) {
#pragma unroll
                for (int j = 0; j < 4; ++j) {
                    int r = nq * 4 + j;
                    ushort pk[8];
#pragma unroll
                    for (int kk = 0; kk < 8; ++kk) pk[kk] = f2bf(((const float*)&breg[kk])[j]);
                    int cb = (kb * 2) ^ ((r & 7) << 4);
                    *(uint4*)(LBo + r * 128 + cb) = *(uint4*)pk;
                }
            }
            VMCNT(0);
            __syncthreads();
            d ^= 1;
        }

        int rbase = bm + wrow * 128 + (lane >> 4) * 4;
        int cbase = bn + wcol * 64 + (lane & 15);
#pragma unroll
        for (int m = 0; m < 8; ++m)
#pragma unroll
            for (int n = 0; n < 4; ++n) {
                int col = cbase + n * 16;
#pragma unroll
                for (int r = 0; r < 4; ++r)
                    Ob[(size_t)(rbase + m * 16 + r) * DIM + col] = f2bf(acc[m][n][r]);
            }
    } else {
        int b2i = b - 256;
        int id = (b2i & 7) * 32 + (b2i >> 3);
        int mt = id >> 4, nt = id & 15;
        int bm = mt * 256, bn = nt * 128;
        const ushort* A = HH + (size_t)NE * CAPE * HID;
        const ushort* B = sw2T;
        size_t a0 = (size_t)(bm + rr) * HID;
        size_t a1 = (size_t)(bm + 64 + rr) * HID;
        size_t a2 = (size_t)(bm + 128 + rr) * HID;
        size_t a3 = (size_t)(bm + 192 + rr) * HID;
        size_t b0 = (size_t)(bn + rr) * HID;
        size_t b1 = (size_t)(bn + 64 + rr) * HID;
        f32x4 acc[8][2];
        core_single<2>(A, B, a0, a1, a2, a3, b0, b1, 0, 0, HID, lds, acc, tid);
        int rbase = bm + wrow * 128 + (lane >> 4) * 4;
        int cbase = bn + wcol * 32 + (lane & 15);
#pragma unroll
        for (int m = 0; m < 8; ++m)
#pragma unroll
            for (int n = 0; n < 2; ++n) {
                int col = cbase + n * 16;
#pragma unroll
                for (int r = 0; r < 4; ++r) {
                    int row = rbase + m * 16 + r;
                    mlpb[(size_t)row * DIM + col] = f2bf(acc[m][n][r] * coefo[2 * row + 1]);
                }
            }
    }
}

// -------- final combine (pure write): out = mlp + coef0*(w0*ye[s0] + w1*ye[s1]) --------
__global__ __launch_bounds__(256) void combine_kernel(
    const ushort* __restrict__ ye, const ushort* __restrict__ mlpb,
    const int* __restrict__ sidx, const float* __restrict__ swt,
    const float* __restrict__ coefo, float* __restrict__ out)
{
    int idx = blockIdx.x * 256 + threadIdx.x;
    int t = idx >> 9;
    int d = (idx & 511) << 2;
    int s0 = sidx[t * 2], s1 = sidx[t * 2 + 1];
    float c0 = coefo[t * 2];
    float w0 = swt[t * 2] * c0, w1 = swt[t * 2 + 1] * c0;
    uint2 mb = *(const uint2*)(mlpb + (size_t)t * DIM + d);
    const ushort* mp = (const ushort*)&mb;
    float4 v;
    v.x = bf2f(mp[0]); v.y = bf2f(mp[1]); v.z = bf2f(mp[2]); v.w = bf2f(mp[3]);
    if (s0 >= 0) {
        uint2 y = *(const uint2*)(ye + (size_t)s0 * DIM + d);
        const ushort* yp = (const ushort*)&y;
        v.x += w0 * bf2f(yp[0]); v.y += w0 * bf2f(yp[1]);
        v.z += w0 * bf2f(yp[2]); v.w += w0 * bf2f(yp[3]);
    }
    if (s1 >= 0) {
        uint2 y = *(const uint2*)(ye + (size_t)s1 * DIM + d);
        const ushort* yp = (const ushort*)&y;
        v.x += w1 * bf2f(yp[0]); v.y += w1 * bf2f(yp[1]);
        v.z += w1 * bf2f(yp[2]); v.w += w1 * bf2f(yp[3]);
    }
    *(float4*)(out + (size_t)t * DIM + d) = v;
}

extern "C" void kernel_launch(void* const* d_in, const int* in_sizes, int n_in,
                              void* d_out, int out_size, void* d_ws, size_t ws_size,
                              hipStream_t stream)
{
    const float* x      = (const float*)d_in[0];
    const float* gate_w = (const float*)d_in[1];
    const float* w1     = (const float*)d_in[2];
    const float* w3     = (const float*)d_in[3];
    const float* w2     = (const float*)d_in[4];
    const float* sw1    = (const float*)d_in[5];
    const float* sw3    = (const float*)d_in[6];
    const float* sw2    = (const float*)d_in[7];
    const float* coef_w = (const float*)d_in[8];
    const float* coef_b = (const float*)d_in[9];
    float* out = (float*)d_out;

    char* ws = (char*)d_ws;
    size_t off = 0;
    auto alloc = [&](size_t bytes) -> void* {
        void* p = ws + off;
        off += (bytes + 255) & ~(size_t)255;
        return p;
    };
    int*    nvalid       = (int*)alloc(NE * 4);
    int*    topidx       = (int*)alloc((size_t)T_TOK * 2 * 4);
    float*  gatesw       = (float*)alloc((size_t)T_TOK * 2 * 4);
    float*  coefo        = (float*)alloc((size_t)T_TOK * 2 * 4);
    int*    sidx         = (int*)alloc((size_t)T_TOK * 2 * 4);
    float*  swt          = (float*)alloc((size_t)T_TOK * 2 * 4);
    int*    assign_token = (int*)alloc((size_t)NE * CAPE * 4);
    float*  probs_part   = (float*)alloc((size_t)256 * NE * 4);
    ushort* w1T  = (ushort*)alloc((size_t)NE * HID * DIM * 2);
    ushort* w3T  = (ushort*)alloc((size_t)NE * HID * DIM * 2);
    ushort* sw1T = (ushort*)alloc((size_t)HID * DIM * 2);
    ushort* sw3T = (ushort*)alloc((size_t)HID * DIM * 2);
    ushort* sw2T = (ushort*)alloc((size_t)DIM * HID * 2);
    ushort* xb   = (ushort*)alloc((size_t)T_TOK * DIM * 2);
    size_t HROWS = (size_t)NE * CAPE + T_TOK;
    ushort* HH   = (ushort*)alloc(HROWS * HID * 2);
    ushort* ye   = (ushort*)alloc((size_t)NE * CAPE * DIM * 2);
    ushort* mlpb = (ushort*)alloc((size_t)T_TOK * DIM * 2);

    float* out_tail = out + (size_t)T_TOK * DIM;

    // 1: logits + convert + fused finish (zeroes l_aux)
    logits_kernel<<<T_TOK / 16, 256, 0, stream>>>(
        x, gate_w, coef_w, coef_b, xb, topidx, gatesw, coefo, probs_part, out_tail);
    // 2: scan (16 blocks) + transposes of w1,w3,sw1,sw3,sw2 (2240 blocks)
    scan_transpose<<<NE + 2240, 256, 0, stream>>>(
        topidx, gatesw, probs_part, sidx, swt, assign_token, nvalid, out_tail,
        w1, w3, sw1, sw3, sw2, w1T, w3T, sw1T, sw3T, sw2T);
    // 3: 8-phase up-projection with fused SiLU
    gemm8_up<<<512, 512, 0, stream>>>(xb, w1T, w3T, sw1T, sw3T, assign_token, HH, nvalid);
    // 4: down-projection (expert: 2-phase on raw f32 w2; shared: 8-phase on sw2T)
    gemm8_down<<<512, 512, 0, stream>>>(HH, w2, sw2T, ye, mlpb, coefo, nvalid);
    // 5: pure-write combine
    combine_kernel<<<(T_TOK * (DIM / 4)) / 256, 256, 0, stream>>>(
        ye, mlpb, sidx, swt, coefo, out);
}

// Round 17
// 354.681 us; speedup vs baseline: 1.1359x; 1.1021x over previous
//
#include <hip/hip_runtime.h>
#include <hip/hip_bf16.h>
#include <stdint.h>

#define T_TOK 4096
#define DIM   2048
#define HID   1024
#define NE    16
#define CAPE  512

typedef __bf16 bf16x8 __attribute__((ext_vector_type(8)));
typedef float  f32x4  __attribute__((ext_vector_type(4)));

__device__ __forceinline__ ushort f2bf(float f) {
    union { float f; uint32_t u; } v; v.f = f;
    uint32_t r = (v.u + 0x7FFFu + ((v.u >> 16) & 1u)) >> 16;
    return (ushort)r;
}
__device__ __forceinline__ float bf2f(ushort u) {
    union { uint32_t u; float f; } v; v.u = (uint32_t)u << 16; return v.f;
}
__device__ __forceinline__ void gload16(const void* g, void* lds) {
    __builtin_amdgcn_global_load_lds(
        (const __attribute__((address_space(1))) uint32_t*)g,
        (__attribute__((address_space(3))) uint32_t*)lds, 16, 0, 0);
}
#define VMCNT(n) asm volatile("s_waitcnt vmcnt(" #n ")" ::: "memory")

// ------------ logits + x->bf16 convert: one wave per token (low-VGPR) ------------
__global__ __launch_bounds__(256) void logits_kernel(
    const float* __restrict__ x, const float* __restrict__ gate_w,
    const float* __restrict__ coef_w, float* __restrict__ logits,
    ushort* __restrict__ xb)
{
    int t = blockIdx.x * 4 + (threadIdx.x >> 6);
    int lane = threadIdx.x & 63;
    const float* xr = x + (size_t)t * DIM;
    float acc[18];
#pragma unroll
    for (int o = 0; o < 18; ++o) acc[o] = 0.f;
#pragma unroll
    for (int g = 0; g < DIM / 512; ++g) {
        int d = g * 512 + lane * 8;
        float4 a = *(const float4*)(xr + d);
        float4 b4 = *(const float4*)(xr + d + 4);
        float xv[8] = {a.x, a.y, a.z, a.w, b4.x, b4.y, b4.z, b4.w};
        ushort ob[8];
#pragma unroll
        for (int j = 0; j < 8; ++j) {
            const float* gw = gate_w + (size_t)(d + j) * NE;
#pragma unroll
            for (int o = 0; o < NE; ++o) acc[o] += xv[j] * gw[o];
            acc[16] += xv[j] * coef_w[(d + j) * 2 + 0];
            acc[17] += xv[j] * coef_w[(d + j) * 2 + 1];
            ob[j] = f2bf(xv[j]);
        }
        *(uint4*)(xb + (size_t)t * DIM + d) = *(uint4*)ob;
    }
#pragma unroll
    for (int off = 32; off > 0; off >>= 1) {
#pragma unroll
        for (int o = 0; o < 18; ++o) acc[o] += __shfl_down(acc[o], off, 64);
    }
    if (lane == 0) {
#pragma unroll
        for (int o = 0; o < 18; ++o) logits[(size_t)t * 18 + o] = acc[o];
    }
}

// ---------------- finish: one thread per token; 16 blocks ----------------
__global__ __launch_bounds__(256) void finish_kernel(
    const float* __restrict__ logits, const float* __restrict__ coef_b,
    int* __restrict__ topidx, float* __restrict__ gatesw,
    float* __restrict__ coefo, float* __restrict__ probs_part,
    float* __restrict__ laux)
{
    __shared__ float wred[4][NE];
    int t = blockIdx.x * 256 + threadIdx.x;
    float lg[18];
#pragma unroll
    for (int o = 0; o < 18; ++o) lg[o] = logits[(size_t)t * 18 + o];
    float p[NE];
    float m = lg[0];
#pragma unroll
    for (int e = 1; e < NE; ++e) m = fmaxf(m, lg[e]);
    float ssum = 0.f;
#pragma unroll
    for (int e = 0; e < NE; ++e) { p[e] = expf(lg[e] - m); ssum += p[e]; }
    float inv = 1.f / ssum;
#pragma unroll
    for (int e = 0; e < NE; ++e) p[e] *= inv;
    int i1 = 0;
#pragma unroll
    for (int e = 1; e < NE; ++e) if (p[e] > p[i1]) i1 = e;
    int i2 = -1;
#pragma unroll
    for (int e = 0; e < NE; ++e) { if (e == i1) continue; if (i2 < 0 || p[e] > p[i2]) i2 = e; }
    float g0 = p[i1], g1 = p[i2], gs = g0 + g1;
    topidx[t * 2 + 0] = i1; topidx[t * 2 + 1] = i2;
    gatesw[t * 2 + 0] = g0 / gs; gatesw[t * 2 + 1] = g1 / gs;
    float c0 = lg[16] + coef_b[0], c1 = lg[17] + coef_b[1];
    float cm = fmaxf(c0, c1);
    float e0 = expf(c0 - cm), e1 = expf(c1 - cm);
    float cs = e0 + e1;
    coefo[t * 2 + 0] = e0 / cs; coefo[t * 2 + 1] = e1 / cs;

    float r[NE];
#pragma unroll
    for (int e = 0; e < NE; ++e) r[e] = p[e];
#pragma unroll
    for (int off = 32; off > 0; off >>= 1) {
#pragma unroll
        for (int e = 0; e < NE; ++e) r[e] += __shfl_down(r[e], off, 64);
    }
    int wv = threadIdx.x >> 6, ln = threadIdx.x & 63;
    if (ln == 0) {
#pragma unroll
        for (int e = 0; e < NE; ++e) wred[wv][e] = r[e];
    }
    __syncthreads();
    if (threadIdx.x < NE)
        probs_part[blockIdx.x * NE + threadIdx.x] =
            wred[0][threadIdx.x] + wred[1][threadIdx.x]
          + wred[2][threadIdx.x] + wred[3][threadIdx.x];
    if (blockIdx.x == 0 && threadIdx.x == 0) laux[0] = 0.f;
}

// ==== merged scan (blocks 0..15) + weight transposes (w1,w3,sw1,sw3,sw2) ====
__global__ __launch_bounds__(256) void scan_transpose(
    const int* __restrict__ topidx, const float* __restrict__ gatesw,
    const float* __restrict__ probs_part,
    int* __restrict__ sidx, float* __restrict__ swt,
    int* __restrict__ assign_token, int* __restrict__ nvalid,
    float* __restrict__ out_tail,
    const float* __restrict__ w1, const float* __restrict__ w3,
    const float* __restrict__ sw1, const float* __restrict__ sw3,
    const float* __restrict__ sw2,
    ushort* __restrict__ w1T, ushort* __restrict__ w3T,
    ushort* __restrict__ sw1T, ushort* __restrict__ sw3T, ushort* __restrict__ sw2T)
{
    __shared__ __align__(16) ushort tile[128][264];
    int tid = threadIdx.x;

    if (blockIdx.x < NE) {
        __shared__ int wcnt[4];
        __shared__ float fred[4];
        __shared__ int runs;
        __shared__ int cnt0s;
        int e = blockIdx.x;
        int wv = tid >> 6, ln = tid & 63;
        unsigned long long ltmask = (1ull << ln) - 1ull;
        if (tid == 0) runs = 0;
        __syncthreads();
        for (int kk = 0; kk < 2; ++kk) {
            for (int c = 0; c < T_TOK; c += 256) {
                int t = c + tid;
                bool m = (topidx[t * 2 + kk] == e);
                unsigned long long b = __ballot(m);
                int within = __popcll(b & ltmask);
                if (ln == 0) wcnt[wv] = __popcll(b);
                __syncthreads();
                int cross = 0;
                for (int w = 0; w < wv; ++w) cross += wcnt[w];
                int pos = runs + cross + within;
                if (m) {
                    bool keep = pos < CAPE;
                    sidx[t * 2 + kk] = keep ? (e * CAPE + pos) : -1;
                    swt[t * 2 + kk] = keep ? gatesw[t * 2 + kk] : 0.f;
                    if (keep) assign_token[e * CAPE + pos] = t;
                }
                __syncthreads();
                if (tid == 0) runs += wcnt[0] + wcnt[1] + wcnt[2] + wcnt[3];
                __syncthreads();
            }
            if (kk == 0 && tid == 0) cnt0s = runs;
            __syncthreads();
        }
        for (int p = runs + tid; p < CAPE; p += 256)
            assign_token[e * CAPE + p] = 0;
        float val = (tid < 16) ? probs_part[tid * NE + e] : 0.f;
#pragma unroll
        for (int off = 32; off > 0; off >>= 1) val += __shfl_down(val, off, 64);
        if (ln == 0) fred[wv] = val;
        __syncthreads();
        if (tid == 0) {
            float psum = fred[0] + fred[1] + fred[2] + fred[3];
            int total = runs;
            nvalid[e] = min(CAPE, total);
            out_tail[1 + e] = (float)total;
            float term = (psum / (float)T_TOK) * ((float)cnt0s / (float)T_TOK) * (float)NE;
            atomicAdd(&out_tail[0], term);
        }
        return;
    }

    int id = blockIdx.x - NE;
    const float* in; ushort* outp; int R, C, tx, ty;
    if (id < 2048) {
        int seg = id >> 10;          // 0:w1 1:w3 (1024 tiles each)
        int rem = id & 1023;
        int e = rem >> 6;
        int r2 = rem & 63;
        R = DIM; C = HID; tx = r2 & 7; ty = r2 >> 3;
        in   = (seg ? w3 : w1) + (size_t)e * DIM * HID;
        outp = (seg ? w3T : w1T) + (size_t)e * HID * DIM;
    } else {
        int id2 = id - 2048;
        int seg = id2 >> 6;          // 0:sw1 1:sw3 2:sw2
        int r2 = id2 & 63;
        if (seg < 2) {
            R = DIM; C = HID; tx = r2 & 7; ty = r2 >> 3;
            in = seg ? sw3 : sw1; outp = seg ? sw3T : sw1T;
        } else {
            R = HID; C = DIM; tx = r2 & 3; ty = r2 >> 2;
            in = sw2; outp = sw2T;
        }
    }
    int r0 = tx * 256, c0 = ty * 128;
    int t31 = tid & 31, t8 = tid >> 5;

#pragma unroll
    for (int it = 0; it < 8; ++it) {
        int r4 = (it * 8 + t8) * 4;
        int c4 = t31 * 4;
        const float* ip = in + (size_t)(r0 + r4) * C + c0 + c4;
        float va[4][4];
        *(float4*)va[0] = *(const float4*)(ip);
        *(float4*)va[1] = *(const float4*)(ip + C);
        *(float4*)va[2] = *(const float4*)(ip + 2 * (size_t)C);
        *(float4*)va[3] = *(const float4*)(ip + 3 * (size_t)C);
#pragma unroll
        for (int j = 0; j < 4; ++j) {
            uint2 u;
            u.x = (uint32_t)f2bf(va[0][j]) | ((uint32_t)f2bf(va[1][j]) << 16);
            u.y = (uint32_t)f2bf(va[2][j]) | ((uint32_t)f2bf(va[3][j]) << 16);
            *(uint2*)&tile[c4 + j][r4] = u;
        }
    }
    __syncthreads();

#pragma unroll
    for (int it = 0; it < 16; ++it) {
        int c = it * 8 + t8;
        int k = t31 * 8;
        uint4 o = *(const uint4*)&tile[c][k];
        *(uint4*)(outp + (size_t)(c0 + c) * R + r0 + k) = o;
    }
}

// ================= GEMM cores =================
__device__ __forceinline__ void stage_half_off(
    const ushort* __restrict__ G, int k0, char* region, int tid,
    size_t off0, size_t off1)
{
#pragma unroll
    for (int q = 0; q < 2; ++q) {
        int c = q * 512 + tid;
        int row = c >> 3;
        int cb = (c & 7) << 4;
        int scb = cb ^ ((row & 7) << 4);
        const ushort* src = G + (q ? off1 : off0) + k0 + (scb >> 1);
        gload16(src, region + ((c - (tid & 63)) << 4));
    }
}

__device__ __forceinline__ bf16x8 ldfrag(const char* lds, int region, int row, int cb) {
    return *(const bf16x8*)(lds + region + row * 128 + (cb ^ ((row & 7) << 4)));
}

// ---- 8-phase single-B core (shared down path, NB=2) ----
template<int NB>
__device__ __forceinline__ void core_single(
    const ushort* __restrict__ A, const ushort* __restrict__ B,
    size_t a0, size_t a1, size_t a2, size_t a3,
    size_t b0, size_t b1, size_t b2, size_t b3,
    int K, char* lds, f32x4 (&acc)[8][NB], int tid)
{
    const int DB = 32768 + NB * 8192;
    int lane = tid & 63;
    int wid = tid >> 6;
    int wrow = wid >> 2, wcol = wid & 3;
    int l15 = lane & 15, hi = lane >> 4;

#pragma unroll
    for (int m = 0; m < 8; ++m)
#pragma unroll
        for (int n = 0; n < NB; ++n)
            acc[m][n] = (f32x4){0.f, 0.f, 0.f, 0.f};

    int nj = K >> 7;

    stage_half_off(A, 0, lds + 0,           tid, a0, a1);
    stage_half_off(A, 0, lds + 16384,       tid, a2, a3);
    stage_half_off(B, 0, lds + 32768,       tid, b0, b1);
    if (NB == 4) stage_half_off(B, 0, lds + 32768 + 16384, tid, b2, b3);
    stage_half_off(B, 64, lds + DB + 32768, tid, b0, b1);
    if (NB == 4) stage_half_off(B, 64, lds + DB + 32768 + 16384, tid, b2, b3);
    if (NB == 4) VMCNT(4); else VMCNT(2);
    __builtin_amdgcn_s_barrier();
    __builtin_amdgcn_sched_barrier(0);

    for (int j = 0; j < nj; ++j) {
        int k1 = (2 * j + 1) << 6, k2 = (2 * j + 2) << 6, k3 = (2 * j + 3) << 6;
        bool st = (j < nj - 1);
#pragma unroll
        for (int d = 0; d < 2; ++d) {
            char* LA = lds + d * DB;
            char* LB = LA + 32768;
            char* LAo = lds + (d ^ 1) * DB;
            bf16x8 bf[NB][2];
#pragma unroll
            for (int p = 0; p < 4; ++p) {
                if (p == 0) {
#pragma unroll
                    for (int n = 0; n < NB; ++n)
#pragma unroll
                        for (int ks = 0; ks < 2; ++ks)
                            bf[n][ks] = ldfrag(LB, 0, wcol * (16 * NB) + n * 16 + l15, ks * 64 + hi * 16);
                }
                bf16x8 af[2][2];
#pragma unroll
                for (int i = 0; i < 2; ++i)
#pragma unroll
                    for (int ks = 0; ks < 2; ++ks)
                        af[i][ks] = ldfrag(LA, 0, wrow * 128 + (2 * p + i) * 16 + l15, ks * 64 + hi * 16);
                if (d == 0) {
                    if (p == 0)      stage_half_off(A, k1, LAo,         tid, a0, a1);
                    else if (p == 1) stage_half_off(A, k1, LAo + 16384, tid, a2, a3);
                    else if (p == 2) { if (st) stage_half_off(B, k2, LB, tid, b0, b1); }
                    else             { if (st && NB == 4) stage_half_off(B, k2, LB + 16384, tid, b2, b3); }
                } else {
                    if (st) {
                        if (p == 0)      stage_half_off(A, k2, LAo,         tid, a0, a1);
                        else if (p == 1) stage_half_off(A, k2, LAo + 16384, tid, a2, a3);
                        else if (p == 2) stage_half_off(B, k3, LB, tid, b0, b1);
                        else             { if (NB == 4) stage_half_off(B, k3, LB + 16384, tid, b2, b3); }
                    }
                }
                __builtin_amdgcn_s_barrier();
                if (p == 3) {
                    if (d == 0) {
                        if (st) { if (NB == 4) VMCNT(4); else VMCNT(2); }
                        else    VMCNT(0);
                    } else if (st) {
                        if (NB == 4) VMCNT(4); else VMCNT(2);
                    }
                }
                asm volatile("s_waitcnt lgkmcnt(0)" ::: "memory");
                __builtin_amdgcn_sched_barrier(0);
                __builtin_amdgcn_s_setprio(1);
#pragma unroll
                for (int i = 0; i < 2; ++i)
#pragma unroll
                    for (int n = 0; n < NB; ++n)
#pragma unroll
                        for (int ks = 0; ks < 2; ++ks)
                            acc[2 * p + i][n] = __builtin_amdgcn_mfma_f32_16x16x32_bf16(
                                af[i][ks], bf[n][ks], acc[2 * p + i][n], 0, 0, 0);
                __builtin_amdgcn_s_setprio(0);
                __builtin_amdgcn_s_barrier();
                __builtin_amdgcn_sched_barrier(0);
            }
        }
    }
}

// ---- 8-phase dual-B core (up path) ----
template<int NM>
__device__ __forceinline__ void core_dual(
    const ushort* __restrict__ A, const ushort* __restrict__ B1,
    const ushort* __restrict__ B3,
    size_t a0, size_t a1, size_t a2, size_t a3,
    size_t b0, size_t b1,
    int K, char* lds, f32x4 (&acc1)[8][NM], f32x4 (&acc3)[8][NM], int tid)
{
    const int DB = 32768 + NM * 16384;
    int lane = tid & 63;
    int wid = tid >> 6;
    int wrow = wid >> 2, wcol = wid & 3;
    int l15 = lane & 15, hi = lane >> 4;

#pragma unroll
    for (int m = 0; m < 8; ++m)
#pragma unroll
        for (int n = 0; n < NM; ++n) {
            acc1[m][n] = (f32x4){0.f, 0.f, 0.f, 0.f};
            acc3[m][n] = (f32x4){0.f, 0.f, 0.f, 0.f};
        }

    int nj = K >> 7;

    stage_half_off(A, 0, lds + 0,     tid, a0, a1);
    stage_half_off(A, 0, lds + 16384, tid, a2, a3);
    stage_half_off(B1, 0, lds + 32768, tid, b0, b1);
    if (NM == 2) stage_half_off(B3, 0, lds + 32768 + 16384, tid, b0, b1);
    stage_half_off(B1, 64, lds + DB + 32768, tid, b0, b1);
    if (NM == 2) stage_half_off(B3, 64, lds + DB + 32768 + 16384, tid, b0, b1);
    if (NM == 2) VMCNT(4); else VMCNT(2);
    __builtin_amdgcn_s_barrier();
    __builtin_amdgcn_sched_barrier(0);

    for (int j = 0; j < nj; ++j) {
        int k1 = (2 * j + 1) << 6, k2 = (2 * j + 2) << 6, k3 = (2 * j + 3) << 6;
        bool st = (j < nj - 1);
#pragma unroll
        for (int d = 0; d < 2; ++d) {
            char* LA = lds + d * DB;
            char* LB = LA + 32768;
            char* LAo = lds + (d ^ 1) * DB;
            bf16x8 bf1[NM][2], bf3[NM][2];
#pragma unroll
            for (int p = 0; p < 4; ++p) {
                if (p == 0) {
#pragma unroll
                    for (int n = 0; n < NM; ++n)
#pragma unroll
                        for (int ks = 0; ks < 2; ++ks) {
                            int brow = wcol * (16 * NM) + n * 16 + l15;
                            bf1[n][ks] = ldfrag(LB, 0, brow,           ks * 64 + hi * 16);
                            bf3[n][ks] = ldfrag(LB, 0, brow + NM * 64, ks * 64 + hi * 16);
                        }
                }
                bf16x8 af[2][2];
#pragma unroll
                for (int i = 0; i < 2; ++i)
#pragma unroll
                    for (int ks = 0; ks < 2; ++ks)
                        af[i][ks] = ldfrag(LA, 0, wrow * 128 + (2 * p + i) * 16 + l15, ks * 64 + hi * 16);
                if (d == 0) {
                    if (p == 0)      stage_half_off(A, k1, LAo,         tid, a0, a1);
                    else if (p == 1) stage_half_off(A, k1, LAo + 16384, tid, a2, a3);
                    else if (p == 2) { if (st) stage_half_off(B1, k2, LB, tid, b0, b1); }
                    else             { if (st && NM == 2) stage_half_off(B3, k2, LB + 16384, tid, b0, b1); }
                } else {
                    if (st) {
                        if (p == 0)      stage_half_off(A, k2, LAo,         tid, a0, a1);
                        else if (p == 1) stage_half_off(A, k2, LAo + 16384, tid, a2, a3);
                        else if (p == 2) stage_half_off(B1, k3, LB, tid, b0, b1);
                        else             { if (NM == 2) stage_half_off(B3, k3, LB + 16384, tid, b0, b1); }
                    }
                }
                __builtin_amdgcn_s_barrier();
                if (p == 3) {
                    if (d == 0) {
                        if (st) { if (NM == 2) VMCNT(4); else VMCNT(2); }
                        else    VMCNT(0);
                    } else if (st) {
                        if (NM == 2) VMCNT(4); else VMCNT(2);
                    }
                }
                asm volatile("s_waitcnt lgkmcnt(0)" ::: "memory");
                __builtin_amdgcn_sched_barrier(0);
                __builtin_amdgcn_s_setprio(1);
#pragma unroll
                for (int i = 0; i < 2; ++i)
#pragma unroll
                    for (int n = 0; n < NM; ++n)
#pragma unroll
                        for (int ks = 0; ks < 2; ++ks) {
                            acc1[2 * p + i][n] = __builtin_amdgcn_mfma_f32_16x16x32_bf16(
                                af[i][ks], bf1[n][ks], acc1[2 * p + i][n], 0, 0, 0);
                            acc3[2 * p + i][n] = __builtin_amdgcn_mfma_f32_16x16x32_bf16(
                                af[i][ks], bf3[n][ks], acc3[2 * p + i][n], 0, 0, 0);
                        }
                __builtin_amdgcn_s_setprio(0);
                __builtin_amdgcn_s_barrier();
                __builtin_amdgcn_sched_barrier(0);
            }
        }
    }
}

// up-projection, fused SiLU: 512 blocks = 256 expert (wide) + 256 shared (narrow)
__global__ __launch_bounds__(512, 2) void gemm8_up(
    const ushort* __restrict__ xb,
    const ushort* __restrict__ w1T, const ushort* __restrict__ w3T,
    const ushort* __restrict__ sw1T, const ushort* __restrict__ sw3T,
    const int* __restrict__ assign_token,
    ushort* __restrict__ HH, const int* __restrict__ nvalid)
{
    __shared__ __align__(16) char lds[131072];
    int b = blockIdx.x;
    int tid = threadIdx.x;
    int rr = tid >> 3;
    int lane = tid & 63, wid = tid >> 6;
    int wrow = wid >> 2, wcol = wid & 3;

    if (b < 256) {
        int id = (b & 7) * 32 + (b >> 3);
        int e = id >> 4, rem = id & 15;
        int mt = rem >> 3, nt = rem & 7;
        int bm = mt * 256, bn = nt * 128;
        if (bm >= nvalid[e]) return;
        const int* at = assign_token + e * CAPE + bm;
        size_t a0 = (size_t)at[rr] * DIM;
        size_t a1 = (size_t)at[64 + rr] * DIM;
        size_t a2 = (size_t)at[128 + rr] * DIM;
        size_t a3 = (size_t)at[192 + rr] * DIM;
        const ushort* B1 = w1T + (size_t)e * HID * DIM;
        const ushort* B3 = w3T + (size_t)e * HID * DIM;
        size_t b0 = (size_t)(bn + rr) * DIM;
        size_t b1 = (size_t)(bn + 64 + rr) * DIM;
        f32x4 acc1[8][2], acc3[8][2];
        core_dual<2>(xb, B1, B3, a0, a1, a2, a3, b0, b1, DIM, lds, acc1, acc3, tid);
        ushort* O = HH + (size_t)e * CAPE * HID;
        int rbase = bm + wrow * 128 + (lane >> 4) * 4;
        int cbase = bn + wcol * 32 + (lane & 15);
#pragma unroll
        for (int m = 0; m < 8; ++m)
#pragma unroll
            for (int n = 0; n < 2; ++n) {
                int col = cbase + n * 16;
#pragma unroll
                for (int r = 0; r < 4; ++r) {
                    float g = acc1[m][n][r];
                    float s = g / (1.f + __expf(-g));
                    O[(size_t)(rbase + m * 16 + r) * HID + col] = f2bf(s * acc3[m][n][r]);
                }
            }
    } else {
        int b2 = b - 256;
        int id = (b2 & 7) * 32 + (b2 >> 3);
        int mt = id >> 4, nt = id & 15;
        int bm = mt * 256, bn = nt * 64;
        size_t a0 = (size_t)(bm + rr) * DIM;
        size_t a1 = (size_t)(bm + 64 + rr) * DIM;
        size_t a2 = (size_t)(bm + 128 + rr) * DIM;
        size_t a3 = (size_t)(bm + 192 + rr) * DIM;
        size_t b0 = (size_t)(bn + rr) * DIM;
        size_t b1 = (size_t)(sw3T - sw1T) + (size_t)(bn + rr) * DIM;
        f32x4 acc1[8][1], acc3[8][1];
        core_dual<1>(xb, sw1T, sw1T, a0, a1, a2, a3, b0, b1, DIM, lds, acc1, acc3, tid);
        ushort* O = HH + (size_t)NE * CAPE * HID;
        int rbase = bm + wrow * 128 + (lane >> 4) * 4;
        int col = bn + wcol * 16 + (lane & 15);
#pragma unroll
        for (int m = 0; m < 8; ++m)
#pragma unroll
            for (int r = 0; r < 4; ++r) {
                float g = acc1[m][0][r];
                float s = g / (1.f + __expf(-g));
                O[(size_t)(rbase + m * 16 + r) * HID + col] = f2bf(s * acc3[m][0][r]);
            }
    }
}

// down-projection: 512 blocks.
// blocks [0,256): expert, 2-phase dbuf, B = raw f32 w2 [K][N] reg-staged -> ye bf16
// blocks [256,512): shared, 8-phase on sw2T -> mlpb bf16
__global__ __launch_bounds__(512, 2) void gemm8_down(
    const ushort* __restrict__ HH, const float* __restrict__ w2f,
    const ushort* __restrict__ sw2T, ushort* __restrict__ ye,
    ushort* __restrict__ mlpb, const float* __restrict__ coefo,
    const int* __restrict__ nvalid)
{
    __shared__ __align__(16) char lds[131072];
    int b = blockIdx.x;
    int tid = threadIdx.x;
    int rr = tid >> 3;
    int lane = tid & 63, wid = tid >> 6;
    int wrow = wid >> 2, wcol = wid & 3;

    if (b < 256) {
        int id = (b & 7) * 32 + (b >> 3);
        int e = id >> 4, rem = id & 15;
        int mt = rem >> 3, nt = rem & 7;
        int bm = mt * 256, bn = nt * 256;
        if (bm >= nvalid[e]) return;
        const ushort* A = HH + (size_t)e * CAPE * HID;
        const float*  W = w2f + (size_t)e * HID * DIM;
        ushort* Ob = ye + (size_t)e * CAPE * DIM;
        size_t a0 = (size_t)(bm + rr) * HID;
        size_t a1 = (size_t)(bm + 64 + rr) * HID;
        size_t a2 = (size_t)(bm + 128 + rr) * HID;
        size_t a3 = (size_t)(bm + 192 + rr) * HID;
        int nq = tid & 63;
        int kb = (tid >> 6) * 8;
        int l15 = lane & 15, hi = lane >> 4;

        f32x4 acc[8][4];
#pragma unroll
        for (int m = 0; m < 8; ++m)
#pragma unroll
            for (int n = 0; n < 4; ++n)
                acc[m][n] = (f32x4){0.f, 0.f, 0.f, 0.f};

        float4 breg[8];
        stage_half_off(A, 0, lds + 0,     tid, a0, a1);
        stage_half_off(A, 0, lds + 16384, tid, a2, a3);
        {
            const float* src = W + (size_t)kb * DIM + bn + nq * 4;
#pragma unroll
            for (int kk = 0; kk < 8; ++kk)
                breg[kk] = *(const float4*)(src + (size_t)kk * DIM);
        }
        {
            char* LB = lds + 32768;
#pragma unroll
            for (int j = 0; j < 4; ++j) {
                int r = nq * 4 + j;
                ushort pk[8];
#pragma unroll
                for (int kk = 0; kk < 8; ++kk) pk[kk] = f2bf(((const float*)&breg[kk])[j]);
                int cb = (kb * 2) ^ ((r & 7) << 4);
                *(uint4*)(LB + r * 128 + cb) = *(uint4*)pk;
            }
        }
        VMCNT(0);
        __syncthreads();

        int d = 0;
        for (int t = 0; t < HID / 64; ++t) {
            bool pf = (t < HID / 64 - 1);
            char* LA = lds + d * 65536;
            char* LB = LA + 32768;
            char* LAo = lds + (d ^ 1) * 65536;
            char* LBo = LAo + 32768;
            if (pf) {
                int k0 = (t + 1) * 64;
                stage_half_off(A, k0, LAo,         tid, a0, a1);
                stage_half_off(A, k0, LAo + 16384, tid, a2, a3);
                const float* src = W + (size_t)(k0 + kb) * DIM + bn + nq * 4;
#pragma unroll
                for (int kk = 0; kk < 8; ++kk)
                    breg[kk] = *(const float4*)(src + (size_t)kk * DIM);
            }
#pragma unroll
            for (int ks = 0; ks < 2; ++ks) {
                bf16x8 af[8], bf[4];
#pragma unroll
                for (int m = 0; m < 8; ++m)
                    af[m] = ldfrag(LA, 0, wrow * 128 + m * 16 + l15, ks * 64 + hi * 16);
#pragma unroll
                for (int n = 0; n < 4; ++n)
                    bf[n] = ldfrag(LB, 0, wcol * 64 + n * 16 + l15, ks * 64 + hi * 16);
#pragma unroll
                for (int m = 0; m < 8; ++m)
#pragma unroll
                    for (int n = 0; n < 4; ++n)
                        acc[m][n] = __builtin_amdgcn_mfma_f32_16x16x32_bf16(
                            af[m], bf[n], acc[m][n], 0, 0, 0);
            }
            if (pf) {
#pragma unroll
                for (int j = 0; j < 4; ++j) {
                    int r = nq * 4 + j;
                    ushort pk[8];
#pragma unroll
                    for (int kk = 0; kk < 8; ++kk) pk[kk] = f2bf(((const float*)&breg[kk])[j]);
                    int cb = (kb * 2) ^ ((r & 7) << 4);
                    *(uint4*)(LBo + r * 128 + cb) = *(uint4*)pk;
                }
            }
            VMCNT(0);
            __syncthreads();
            d ^= 1;
        }

        int rbase = bm + wrow * 128 + (lane >> 4) * 4;
        int cbase = bn + wcol * 64 + (lane & 15);
#pragma unroll
        for (int m = 0; m < 8; ++m)
#pragma unroll
            for (int n = 0; n < 4; ++n) {
                int col = cbase + n * 16;
#pragma unroll
                for (int r = 0; r < 4; ++r)
                    Ob[(size_t)(rbase + m * 16 + r) * DIM + col] = f2bf(acc[m][n][r]);
            }
    } else {
        int b2i = b - 256;
        int id = (b2i & 7) * 32 + (b2i >> 3);
        int mt = id >> 4, nt = id & 15;
        int bm = mt * 256, bn = nt * 128;
        const ushort* A = HH + (size_t)NE * CAPE * HID;
        const ushort* B = sw2T;
        size_t a0 = (size_t)(bm + rr) * HID;
        size_t a1 = (size_t)(bm + 64 + rr) * HID;
        size_t a2 = (size_t)(bm + 128 + rr) * HID;
        size_t a3 = (size_t)(bm + 192 + rr) * HID;
        size_t b0 = (size_t)(bn + rr) * HID;
        size_t b1 = (size_t)(bn + 64 + rr) * HID;
        f32x4 acc[8][2];
        core_single<2>(A, B, a0, a1, a2, a3, b0, b1, 0, 0, HID, lds, acc, tid);
        int rbase = bm + wrow * 128 + (lane >> 4) * 4;
        int cbase = bn + wcol * 32 + (lane & 15);
#pragma unroll
        for (int m = 0; m < 8; ++m)
#pragma unroll
            for (int n = 0; n < 2; ++n) {
                int col = cbase + n * 16;
#pragma unroll
                for (int r = 0; r < 4; ++r) {
                    int row = rbase + m * 16 + r;
                    mlpb[(size_t)row * DIM + col] = f2bf(acc[m][n][r] * coefo[2 * row + 1]);
                }
            }
    }
}

// -------- final combine (pure write): out = mlp + coef0*(w0*ye[s0] + w1*ye[s1]) --------
__global__ __launch_bounds__(256) void combine_kernel(
    const ushort* __restrict__ ye, const ushort* __restrict__ mlpb,
    const int* __restrict__ sidx, const float* __restrict__ swt,
    const float* __restrict__ coefo, float* __restrict__ out)
{
    int idx = blockIdx.x * 256 + threadIdx.x;
    int t = idx >> 9;
    int d = (idx & 511) << 2;
    int s0 = sidx[t * 2], s1 = sidx[t * 2 + 1];
    float c0 = coefo[t * 2];
    float w0 = swt[t * 2] * c0, w1 = swt[t * 2 + 1] * c0;
    uint2 mb = *(const uint2*)(mlpb + (size_t)t * DIM + d);
    const ushort* mp = (const ushort*)&mb;
    float4 v;
    v.x = bf2f(mp[0]); v.y = bf2f(mp[1]); v.z = bf2f(mp[2]); v.w = bf2f(mp[3]);
    if (s0 >= 0) {
        uint2 y = *(const uint2*)(ye + (size_t)s0 * DIM + d);
        const ushort* yp = (const ushort*)&y;
        v.x += w0 * bf2f(yp[0]); v.y += w0 * bf2f(yp[1]);
        v.z += w0 * bf2f(yp[2]); v.w += w0 * bf2f(yp[3]);
    }
    if (s1 >= 0) {
        uint2 y = *(const uint2*)(ye + (size_t)s1 * DIM + d);
        const ushort* yp = (const ushort*)&y;
        v.x += w1 * bf2f(yp[0]); v.y += w1 * bf2f(yp[1]);
        v.z += w1 * bf2f(yp[2]); v.w += w1 * bf2f(yp[3]);
    }
    *(float4*)(out + (size_t)t * DIM + d) = v;
}

extern "C" void kernel_launch(void* const* d_in, const int* in_sizes, int n_in,
                              void* d_out, int out_size, void* d_ws, size_t ws_size,
                              hipStream_t stream)
{
    const float* x      = (const float*)d_in[0];
    const float* gate_w = (const float*)d_in[1];
    const float* w1     = (const float*)d_in[2];
    const float* w3     = (const float*)d_in[3];
    const float* w2     = (const float*)d_in[4];
    const float* sw1    = (const float*)d_in[5];
    const float* sw3    = (const float*)d_in[6];
    const float* sw2    = (const float*)d_in[7];
    const float* coef_w = (const float*)d_in[8];
    const float* coef_b = (const float*)d_in[9];
    float* out = (float*)d_out;

    char* ws = (char*)d_ws;
    size_t off = 0;
    auto alloc = [&](size_t bytes) -> void* {
        void* p = ws + off;
        off += (bytes + 255) & ~(size_t)255;
        return p;
    };
    int*    nvalid       = (int*)alloc(NE * 4);
    int*    topidx       = (int*)alloc((size_t)T_TOK * 2 * 4);
    float*  gatesw       = (float*)alloc((size_t)T_TOK * 2 * 4);
    float*  coefo        = (float*)alloc((size_t)T_TOK * 2 * 4);
    int*    sidx         = (int*)alloc((size_t)T_TOK * 2 * 4);
    float*  swt          = (float*)alloc((size_t)T_TOK * 2 * 4);
    int*    assign_token = (int*)alloc((size_t)NE * CAPE * 4);
    float*  probs_part   = (float*)alloc((size_t)16 * NE * 4);
    float*  logits       = (float*)alloc((size_t)T_TOK * 18 * 4);
    ushort* w1T  = (ushort*)alloc((size_t)NE * HID * DIM * 2);
    ushort* w3T  = (ushort*)alloc((size_t)NE * HID * DIM * 2);
    ushort* sw1T = (ushort*)alloc((size_t)HID * DIM * 2);
    ushort* sw3T = (ushort*)alloc((size_t)HID * DIM * 2);
    ushort* sw2T = (ushort*)alloc((size_t)DIM * HID * 2);
    ushort* xb   = (ushort*)alloc((size_t)T_TOK * DIM * 2);
    size_t HROWS = (size_t)NE * CAPE + T_TOK;
    ushort* HH   = (ushort*)alloc(HROWS * HID * 2);
    ushort* ye   = (ushort*)alloc((size_t)NE * CAPE * DIM * 2);
    ushort* mlpb = (ushort*)alloc((size_t)T_TOK * DIM * 2);

    float* out_tail = out + (size_t)T_TOK * DIM;

    // 1: logits + x convert (one wave per token, low VGPR)
    logits_kernel<<<T_TOK / 4, 256, 0, stream>>>(x, gate_w, coef_w, logits, xb);
    // 2: finish (softmax/top2/coef; writes probs_part, zeroes l_aux)
    finish_kernel<<<T_TOK / 256, 256, 0, stream>>>(logits, coef_b, topidx, gatesw,
                                                   coefo, probs_part, out_tail);
    // 3: scan (16 blocks) + transposes of w1,w3,sw1,sw3,sw2 (2240 blocks)
    scan_transpose<<<NE + 2240, 256, 0, stream>>>(
        topidx, gatesw, probs_part, sidx, swt, assign_token, nvalid, out_tail,
        w1, w3, sw1, sw3, sw2, w1T, w3T, sw1T, sw3T, sw2T);
    // 4: 8-phase up-projection with fused SiLU
    gemm8_up<<<512, 512, 0, stream>>>(xb, w1T, w3T, sw1T, sw3T, assign_token, HH, nvalid);
    // 5: down-projection (expert: 2-phase on raw f32 w2; shared: 8-phase on sw2T)
    gemm8_down<<<512, 512, 0, stream>>>(HH, w2, sw2T, ye, mlpb, coefo, nvalid);
    // 6: pure-write combine
    combine_kernel<<<(T_TOK * (DIM / 4)) / 256, 256, 0, stream>>>(
        ye, mlpb, sidx, swt, coefo, out);
}